// Round 1
// baseline (31310.172 us; speedup 1.0000x reference)
//
#include <hip/hip_runtime.h>

#define HID 128
#define G3  384   // 3*HID
#define TSTEPS 5

typedef unsigned int  uint;
typedef unsigned short ushort;

typedef float  f32x4  __attribute__((ext_vector_type(4)));
typedef __bf16 bf16x8 __attribute__((ext_vector_type(8)));

union B8u { uint4 u; bf16x8 b; ushort s[8]; };

static __device__ inline ushort f2bf(float f) {
  uint u = __float_as_uint(f);
  uint r = u + 0x7fffu + ((u >> 16) & 1u);   // RTN-even
  return (ushort)(r >> 16);
}
static __device__ inline float bf2f(ushort s) {
  return __uint_as_float(((uint)s) << 16);
}

// ---- once per call: W_comb = W_ih @ W_e (bf16), bvec = W_ih @ b_e, W_hh -> bf16
__global__ __launch_bounds__(128) void k_weights(
    const float* __restrict__ W_e, const float* __restrict__ b_e,
    const float* __restrict__ W_ih, const float* __restrict__ W_hh,
    ushort* __restrict__ Wcomb, ushort* __restrict__ Whh16, float* __restrict__ bvec)
{
  int j = blockIdx.x, t = threadIdx.x;
  if (j < G3) {
    __shared__ float row[HID];
    row[t] = W_ih[j * HID + t];
    __syncthreads();
    float acc = 0.f;
    for (int k = 0; k < HID; ++k) acc = fmaf(row[k], W_e[k * HID + t], acc);
    Wcomb[j * HID + t] = f2bf(acc);
    if (t == 0) {
      float b = 0.f;
      for (int k = 0; k < HID; ++k) b += row[k] * b_e[k];
      bvec[j] = b;
    }
  } else {
    int j2 = j - G3;
    Whh16[j2 * HID + t] = f2bf(W_hh[j2 * HID + t]);
  }
}

__global__ void k_deg(const int* __restrict__ dst, int* __restrict__ deg, int E) {
  int e = blockIdx.x * 256 + threadIdx.x;
  if (e < E) atomicAdd(&deg[dst[e]], 1);
}

__global__ void k_init(const float* __restrict__ m, float* __restrict__ h,
                       ushort* __restrict__ hb, int N) {
  int idx = blockIdx.x * 256 + threadIdx.x;
  if (idx >= N * HID) return;
  int d = idx & (HID - 1);
  float v = (d == 0) ? m[idx >> 7] : 0.f;
  h[idx] = v;
  hb[idx] = f2bf(v);
}

// ---- scatter: hsum[dst] += h_bf16[src]; 16 lanes per edge, fp32 atomics
__global__ __launch_bounds__(256) void k_edge(
    const int* __restrict__ src, const int* __restrict__ dst,
    const ushort* __restrict__ hb, float* __restrict__ hsum, int E)
{
  uint t = blockIdx.x * 256u + threadIdx.x;
  int e = (int)(t >> 4);
  if (e >= E) return;
  int l = (int)(t & 15u);
  int s = src[e], d = dst[e];
  B8u w; w.u = *(const uint4*)(hb + (size_t)s * HID + l * 8);
  float* out = hsum + (size_t)d * HID + l * 8;
#pragma unroll
  for (int i = 0; i < 8; ++i) unsafeAtomicAdd(out + i, bf2f(w.s[i]));
}

__global__ void k_cvt(const float* __restrict__ x, ushort* __restrict__ y, int n4) {
  int i = blockIdx.x * 256 + threadIdx.x;
  if (i >= n4) return;
  float4 v = ((const float4*)x)[i];
  ushort4 o; o.x = f2bf(v.x); o.y = f2bf(v.y); o.z = f2bf(v.z); o.w = f2bf(v.w);
  ((ushort4*)y)[i] = o;
}

// ---- fused GEMM (gi from hsum via Wcomb, gh from h via Whh) + GRU, in-place h
// block = 512 thr (8 waves) over a 16-node strip; wave w owns dims [16w,16w+16)
__global__ __launch_bounds__(512) void k_gru(
    const ushort* __restrict__ hsum16, float* h, ushort* hb,
    const ushort* __restrict__ Wcomb, const ushort* __restrict__ Whh16,
    const float* __restrict__ bvec, const float* __restrict__ b_ih,
    const float* __restrict__ b_hh, const int* __restrict__ deg, int N)
{
  const int n0 = blockIdx.x * 16;
  const int w = threadIdx.x >> 6;
  const int lane = threadIdx.x & 63;
  const int quad = lane >> 4, l16 = lane & 15;
  const int d0 = w * 16;
  const size_t arow = (size_t)(n0 + l16) * HID;

  f32x4 acc[6] = {};   // 0..2: gi r/z/n tiles, 3..5: gh r/z/n tiles
#pragma unroll
  for (int kc = 0; kc < 4; ++kc) {
    int klane = kc * 32 + quad * 8;
    B8u af; af.u = *(const uint4*)(hsum16 + arow + klane);  // A = hsum (bf16)
    B8u hf; hf.u = *(const uint4*)(hb + arow + klane);      // A = h    (bf16)
#pragma unroll
    for (int g = 0; g < 3; ++g) {
      int j = (d0 + g * 128 + l16) * HID + klane;
      B8u bw; bw.u = *(const uint4*)(Wcomb + j);
      acc[g] = __builtin_amdgcn_mfma_f32_16x16x32_bf16(af.b, bw.b, acc[g], 0, 0, 0);
      B8u bh; bh.u = *(const uint4*)(Whh16 + j);
      acc[3 + g] = __builtin_amdgcn_mfma_f32_16x16x32_bf16(hf.b, bh.b, acc[3 + g], 0, 0, 0);
    }
  }

  const int d = d0 + l16;
  const float bir = b_ih[d], biz = b_ih[d + 128], bin_ = b_ih[d + 256];
  const float bhr = b_hh[d], bhz = b_hh[d + 128], bhn = b_hh[d + 256];
  const float vr = bvec[d], vz = bvec[d + 128], vn = bvec[d + 256];

  float hold[4], degf[4];
#pragma unroll
  for (int rg = 0; rg < 4; ++rg) {
    int n = n0 + quad * 4 + rg;
    hold[rg] = h[(size_t)n * HID + d];
    degf[rg] = (float)deg[n];
  }
  __syncthreads();   // all reads of h/hb done before in-place writes
#pragma unroll
  for (int rg = 0; rg < 4; ++rg) {
    float ir = acc[0][rg] + degf[rg] * vr + bir;
    float iz = acc[1][rg] + degf[rg] * vz + biz;
    float in_ = acc[2][rg] + degf[rg] * vn + bin_;
    float hr = acc[3][rg] + bhr;
    float hz = acc[4][rg] + bhz;
    float hn = acc[5][rg] + bhn;
    float r = 1.f / (1.f + __expf(-(ir + hr)));
    float z = 1.f / (1.f + __expf(-(iz + hz)));
    float x2 = in_ + r * hn;
    float e2 = __expf(2.f * x2);
    float nv = 1.f - 2.f / (e2 + 1.f);   // tanh
    float hv = (1.f - z) * nv + z * hold[rg];
    size_t o = (size_t)(n0 + quad * 4 + rg) * HID + d;
    h[o] = hv;
    hb[o] = f2bf(hv);
  }
}

// ---- pooling: graph_ids sorted -> run-length accumulate, few atomics
__global__ __launch_bounds__(128) void k_pool(const float* __restrict__ h,
                                              const int* __restrict__ gid,
                                              float* __restrict__ hg, int N) {
  int d = threadIdx.x;
  int start = blockIdx.x * 500;
  if (start >= N) return;
  int end = min(start + 500, N);
  float acc = 0.f;
  int g = gid[start];
  for (int n = start; n < end; ++n) {
    int gn = gid[n];
    if (gn != g) { unsafeAtomicAdd(&hg[g * HID + d], acc); acc = 0.f; g = gn; }
    acc += fmaxf(h[(size_t)n * HID + d], 0.f);   // relu
  }
  unsafeAtomicAdd(&hg[g * HID + d], acc);
}

__global__ void k_cnt(const int* __restrict__ gid, int* __restrict__ cnt, int N) {
  int n = blockIdx.x * 256 + threadIdx.x;
  if (n < N) atomicAdd(&cnt[gid[n]], 1);
}

__global__ __launch_bounds__(640) void k_cls(const float* __restrict__ hg,
                                             const int* __restrict__ cnt,
                                             const float* __restrict__ Wc,
                                             const float* __restrict__ bc,
                                             float* __restrict__ out, int G) {
  int t = threadIdx.x;
  if (t >= G * 10) return;
  int g = t / 10, c = t % 10;
  float inv = 1.f / fmaxf((float)cnt[g], 1.f);
  float acc = 0.f;
  for (int d = 0; d < HID; ++d) acc = fmaf(hg[g * HID + d], Wc[c * HID + d], acc);
  out[t] = acc * inv + bc[c];
}

extern "C" void kernel_launch(void* const* d_in, const int* in_sizes, int n_in,
                              void* d_out, int out_size, void* d_ws, size_t ws_size,
                              hipStream_t stream) {
  const int N = in_sizes[0];
  const int E = in_sizes[9];
  const float* m    = (const float*)d_in[0];
  const float* W_e  = (const float*)d_in[1];
  const float* b_e  = (const float*)d_in[2];
  const float* W_ih = (const float*)d_in[3];
  const float* b_ih = (const float*)d_in[4];
  const float* W_hh = (const float*)d_in[5];
  const float* b_hh = (const float*)d_in[6];
  const float* W_cls = (const float*)d_in[7];
  const float* b_cls = (const float*)d_in[8];
  const int* src = (const int*)d_in[9];
  const int* dst = (const int*)d_in[10];
  const int* gid = (const int*)d_in[11];
  const int G = out_size / 10;
  float* out = (float*)d_out;

  size_t off = 0;
  auto alloc = [&](size_t b) {
    char* p = (char*)d_ws + off;
    off += (b + 255) & ~(size_t)255;
    return (void*)p;
  };
  float*  h     = (float*) alloc((size_t)N * HID * 4);
  ushort* hb    = (ushort*)alloc((size_t)N * HID * 2);
  float*  hsum  = (float*) alloc((size_t)N * HID * 4);
  ushort* hs16  = (ushort*)alloc((size_t)N * HID * 2);
  int*    deg   = (int*)   alloc((size_t)N * 4);
  ushort* Wcomb = (ushort*)alloc((size_t)G3 * HID * 2);
  ushort* Whh16 = (ushort*)alloc((size_t)G3 * HID * 2);
  float*  bvec  = (float*) alloc((size_t)G3 * 4);
  float*  hg    = (float*) alloc((size_t)G * HID * 4);
  int*    cnt   = (int*)   alloc((size_t)G * 4);
  if (off > ws_size) return;   // workspace too small -> visible failure

  k_weights<<<2 * G3, HID, 0, stream>>>(W_e, b_e, W_ih, W_hh, Wcomb, Whh16, bvec);
  hipMemsetAsync(deg, 0, (size_t)N * 4, stream);
  k_deg<<<(E + 255) / 256, 256, 0, stream>>>(dst, deg, E);
  k_init<<<(N * HID + 255) / 256, 256, 0, stream>>>(m, h, hb, N);

  for (int s = 0; s < TSTEPS; ++s) {
    hipMemsetAsync(hsum, 0, (size_t)N * HID * 4, stream);
    k_edge<<<(int)(((size_t)E * 16 + 255) / 256), 256, 0, stream>>>(src, dst, hb, hsum, E);
    k_cvt<<<(N * HID / 4 + 255) / 256, 256, 0, stream>>>(hsum, hs16, N * HID / 4);
    k_gru<<<N / 16, 512, 0, stream>>>(hs16, h, hb, Wcomb, Whh16, bvec, b_ih, b_hh, deg, N);
  }

  hipMemsetAsync(hg, 0, (size_t)G * HID * 4, stream);
  hipMemsetAsync(cnt, 0, (size_t)G * 4, stream);
  k_cnt<<<(N + 255) / 256, 256, 0, stream>>>(gid, cnt, N);
  k_pool<<<(N + 499) / 500, HID, 0, stream>>>(h, gid, hg, N);
  k_cls<<<1, 640, 0, stream>>>(hg, cnt, W_cls, b_cls, out, G);
}

// Round 2
// 2499.182 us; speedup vs baseline: 12.5282x; 12.5282x over previous
//
#include <hip/hip_runtime.h>

#define HID 128
#define G3  384   // 3*HID
#define TSTEPS 5

typedef unsigned int  uint;
typedef unsigned short ushort;

typedef float  f32x4  __attribute__((ext_vector_type(4)));
typedef __bf16 bf16x8 __attribute__((ext_vector_type(8)));

union B8u { uint4 u; bf16x8 b; ushort s[8]; };

static __device__ inline ushort f2bf(float f) {
  uint u = __float_as_uint(f);
  uint r = u + 0x7fffu + ((u >> 16) & 1u);   // RTN-even
  return (ushort)(r >> 16);
}
static __device__ inline float bf2f(ushort s) {
  return __uint_as_float(((uint)s) << 16);
}

// ---- once per call: W_comb = W_ih @ W_e (bf16), bvec = W_ih @ b_e, W_hh -> bf16
__global__ __launch_bounds__(128) void k_weights(
    const float* __restrict__ W_e, const float* __restrict__ b_e,
    const float* __restrict__ W_ih, const float* __restrict__ W_hh,
    ushort* __restrict__ Wcomb, ushort* __restrict__ Whh16, float* __restrict__ bvec)
{
  int j = blockIdx.x, t = threadIdx.x;
  if (j < G3) {
    __shared__ float row[HID];
    row[t] = W_ih[j * HID + t];
    __syncthreads();
    float acc = 0.f;
    for (int k = 0; k < HID; ++k) acc = fmaf(row[k], W_e[k * HID + t], acc);
    Wcomb[j * HID + t] = f2bf(acc);
    if (t == 0) {
      float b = 0.f;
      for (int k = 0; k < HID; ++k) b += row[k] * b_e[k];
      bvec[j] = b;
    }
  } else {
    int j2 = j - G3;
    Whh16[j2 * HID + t] = f2bf(W_hh[j2 * HID + t]);
  }
}

__global__ void k_deg(const int* __restrict__ dst, int* __restrict__ deg, int E) {
  int e = blockIdx.x * 256 + threadIdx.x;
  if (e < E) atomicAdd(&deg[dst[e]], 1);
}

// single-block exclusive scan of deg -> rowptr (N up to 1024*chunk)
__global__ __launch_bounds__(1024) void k_scan(const int* __restrict__ deg,
                                               int* __restrict__ rowptr, int N) {
  __shared__ int part[1024];
  int t = threadIdx.x;
  int chunk = (N + 1023) / 1024;
  int b = t * chunk, e = min(b + chunk, N);
  if (b > N) { b = N; }
  int s = 0;
  for (int i = b; i < e; ++i) s += deg[i];
  part[t] = s;
  __syncthreads();
  for (int off = 1; off < 1024; off <<= 1) {
    int x = (t >= off) ? part[t - off] : 0;
    __syncthreads();
    part[t] += x;
    __syncthreads();
  }
  int run = part[t] - s;   // exclusive prefix for this chunk
  for (int i = b; i < e; ++i) { rowptr[i] = run; run += deg[i]; }
  if (t == 1023) rowptr[N] = part[1023];
}

__global__ void k_fill(const int* __restrict__ src, const int* __restrict__ dst,
                       const int* __restrict__ rowptr, int* __restrict__ cursor,
                       int* __restrict__ csrc, int E) {
  int e = blockIdx.x * 256 + threadIdx.x;
  if (e >= E) return;
  int d = dst[e];
  int p = atomicAdd(&cursor[d], 1);
  csrc[rowptr[d] + p] = src[e];
}

__global__ void k_init(const float* __restrict__ m, float* __restrict__ h,
                       ushort* __restrict__ hb, int N) {
  int idx = blockIdx.x * 256 + threadIdx.x;
  if (idx >= N * HID) return;
  int d = idx & (HID - 1);
  float v = (d == 0) ? m[idx >> 7] : 0.f;
  h[idx] = v;
  hb[idx] = f2bf(v);
}

// ---- gather: hs16[v] = bf16( sum_{u in N_in(v)} h[u] ); one wave per node,
// lane owns 2 dims (dword = 2 bf16), fp32 accumulate, 2x unroll for MLP
__global__ __launch_bounds__(256) void k_gather(
    const int* __restrict__ rowptr, const int* __restrict__ csrc,
    const ushort* __restrict__ hb, ushort* __restrict__ hs16, int N)
{
  int v = blockIdx.x * 4 + (threadIdx.x >> 6);
  if (v >= N) return;
  int lane = threadIdx.x & 63;
  int beg = rowptr[v], end = rowptr[v + 1];
  float a0 = 0.f, a1 = 0.f, b0 = 0.f, b1 = 0.f;
  int e = beg;
  for (; e + 1 < end; e += 2) {
    int s0 = csrc[e], s1 = csrc[e + 1];
    uint w0 = *(const uint*)(hb + (size_t)s0 * HID + lane * 2);
    uint w1 = *(const uint*)(hb + (size_t)s1 * HID + lane * 2);
    a0 += bf2f((ushort)w0); a1 += bf2f((ushort)(w0 >> 16));
    b0 += bf2f((ushort)w1); b1 += bf2f((ushort)(w1 >> 16));
  }
  if (e < end) {
    int s0 = csrc[e];
    uint w0 = *(const uint*)(hb + (size_t)s0 * HID + lane * 2);
    a0 += bf2f((ushort)w0); a1 += bf2f((ushort)(w0 >> 16));
  }
  a0 += b0; a1 += b1;
  uint o = ((uint)f2bf(a1) << 16) | (uint)f2bf(a0);
  *(uint*)(hs16 + (size_t)v * HID + lane * 2) = o;
}

// ---- fused GEMM (gi from hs16 via Wcomb, gh from hb via Whh) + GRU, in-place h
// block = 512 thr (8 waves) over a 16-node strip; wave w owns dims [16w,16w+16)
__global__ __launch_bounds__(512) void k_gru(
    const ushort* __restrict__ hsum16, float* h, ushort* hb,
    const ushort* __restrict__ Wcomb, const ushort* __restrict__ Whh16,
    const float* __restrict__ bvec, const float* __restrict__ b_ih,
    const float* __restrict__ b_hh, const int* __restrict__ deg, int N)
{
  const int n0 = blockIdx.x * 16;
  const int w = threadIdx.x >> 6;
  const int lane = threadIdx.x & 63;
  const int quad = lane >> 4, l16 = lane & 15;
  const int d0 = w * 16;
  const size_t arow = (size_t)(n0 + l16) * HID;

  f32x4 acc[6] = {};   // 0..2: gi r/z/n tiles, 3..5: gh r/z/n tiles
#pragma unroll
  for (int kc = 0; kc < 4; ++kc) {
    int klane = kc * 32 + quad * 8;
    B8u af; af.u = *(const uint4*)(hsum16 + arow + klane);  // A = hsum (bf16)
    B8u hf; hf.u = *(const uint4*)(hb + arow + klane);      // A = h    (bf16)
#pragma unroll
    for (int g = 0; g < 3; ++g) {
      int j = (d0 + g * 128 + l16) * HID + klane;
      B8u bw; bw.u = *(const uint4*)(Wcomb + j);
      acc[g] = __builtin_amdgcn_mfma_f32_16x16x32_bf16(af.b, bw.b, acc[g], 0, 0, 0);
      B8u bh; bh.u = *(const uint4*)(Whh16 + j);
      acc[3 + g] = __builtin_amdgcn_mfma_f32_16x16x32_bf16(hf.b, bh.b, acc[3 + g], 0, 0, 0);
    }
  }

  const int d = d0 + l16;
  const float bir = b_ih[d], biz = b_ih[d + 128], bin_ = b_ih[d + 256];
  const float bhr = b_hh[d], bhz = b_hh[d + 128], bhn = b_hh[d + 256];
  const float vr = bvec[d], vz = bvec[d + 128], vn = bvec[d + 256];

  float hold[4], degf[4];
#pragma unroll
  for (int rg = 0; rg < 4; ++rg) {
    int n = n0 + quad * 4 + rg;
    hold[rg] = h[(size_t)n * HID + d];
    degf[rg] = (float)deg[n];
  }
  __syncthreads();   // all reads of h/hb done before in-place writes
#pragma unroll
  for (int rg = 0; rg < 4; ++rg) {
    float ir = acc[0][rg] + degf[rg] * vr + bir;
    float iz = acc[1][rg] + degf[rg] * vz + biz;
    float in_ = acc[2][rg] + degf[rg] * vn + bin_;
    float hr = acc[3][rg] + bhr;
    float hz = acc[4][rg] + bhz;
    float hn = acc[5][rg] + bhn;
    float r = 1.f / (1.f + __expf(-(ir + hr)));
    float z = 1.f / (1.f + __expf(-(iz + hz)));
    float x2 = in_ + r * hn;
    float e2 = __expf(2.f * x2);
    float nv = 1.f - 2.f / (e2 + 1.f);   // tanh
    float hv = (1.f - z) * nv + z * hold[rg];
    size_t o = (size_t)(n0 + quad * 4 + rg) * HID + d;
    h[o] = hv;
    hb[o] = f2bf(hv);
  }
}

// ---- pooling: graph_ids sorted -> run-length accumulate, few atomics
__global__ __launch_bounds__(128) void k_pool(const float* __restrict__ h,
                                              const int* __restrict__ gid,
                                              float* __restrict__ hg, int N) {
  int d = threadIdx.x;
  int start = blockIdx.x * 500;
  if (start >= N) return;
  int end = min(start + 500, N);
  float acc = 0.f;
  int g = gid[start];
  for (int n = start; n < end; ++n) {
    int gn = gid[n];
    if (gn != g) { unsafeAtomicAdd(&hg[g * HID + d], acc); acc = 0.f; g = gn; }
    acc += fmaxf(h[(size_t)n * HID + d], 0.f);   // relu
  }
  unsafeAtomicAdd(&hg[g * HID + d], acc);
}

__global__ void k_cnt(const int* __restrict__ gid, int* __restrict__ cnt, int N) {
  int n = blockIdx.x * 256 + threadIdx.x;
  if (n < N) atomicAdd(&cnt[gid[n]], 1);
}

__global__ __launch_bounds__(640) void k_cls(const float* __restrict__ hg,
                                             const int* __restrict__ cnt,
                                             const float* __restrict__ Wc,
                                             const float* __restrict__ bc,
                                             float* __restrict__ out, int G) {
  int t = threadIdx.x;
  if (t >= G * 10) return;
  int g = t / 10, c = t % 10;
  float inv = 1.f / fmaxf((float)cnt[g], 1.f);
  float acc = 0.f;
  for (int d = 0; d < HID; ++d) acc = fmaf(hg[g * HID + d], Wc[c * HID + d], acc);
  out[t] = acc * inv + bc[c];
}

extern "C" void kernel_launch(void* const* d_in, const int* in_sizes, int n_in,
                              void* d_out, int out_size, void* d_ws, size_t ws_size,
                              hipStream_t stream) {
  const int N = in_sizes[0];
  const int E = in_sizes[9];
  const float* m    = (const float*)d_in[0];
  const float* W_e  = (const float*)d_in[1];
  const float* b_e  = (const float*)d_in[2];
  const float* W_ih = (const float*)d_in[3];
  const float* b_ih = (const float*)d_in[4];
  const float* W_hh = (const float*)d_in[5];
  const float* b_hh = (const float*)d_in[6];
  const float* W_cls = (const float*)d_in[7];
  const float* b_cls = (const float*)d_in[8];
  const int* src = (const int*)d_in[9];
  const int* dst = (const int*)d_in[10];
  const int* gid = (const int*)d_in[11];
  const int G = out_size / 10;
  float* out = (float*)d_out;

  size_t off = 0;
  auto alloc = [&](size_t b) {
    char* p = (char*)d_ws + off;
    off += (b + 255) & ~(size_t)255;
    return (void*)p;
  };
  float*  h      = (float*) alloc((size_t)N * HID * 4);
  ushort* hb     = (ushort*)alloc((size_t)N * HID * 2);
  ushort* hs16   = (ushort*)alloc((size_t)N * HID * 2);
  int*    deg    = (int*)   alloc((size_t)N * 4);
  int*    rowptr = (int*)   alloc((size_t)(N + 1) * 4);
  int*    cursor = (int*)   alloc((size_t)N * 4);
  int*    csrc   = (int*)   alloc((size_t)E * 4);
  ushort* Wcomb  = (ushort*)alloc((size_t)G3 * HID * 2);
  ushort* Whh16  = (ushort*)alloc((size_t)G3 * HID * 2);
  float*  bvec   = (float*) alloc((size_t)G3 * 4);
  float*  hg     = (float*) alloc((size_t)G * HID * 4);
  int*    cnt    = (int*)   alloc((size_t)G * 4);
  if (off > ws_size) return;   // workspace too small -> visible failure

  k_weights<<<2 * G3, HID, 0, stream>>>(W_e, b_e, W_ih, W_hh, Wcomb, Whh16, bvec);
  hipMemsetAsync(deg, 0, (size_t)N * 4, stream);
  hipMemsetAsync(cursor, 0, (size_t)N * 4, stream);
  k_deg<<<(E + 255) / 256, 256, 0, stream>>>(dst, deg, E);
  k_scan<<<1, 1024, 0, stream>>>(deg, rowptr, N);
  k_fill<<<(E + 255) / 256, 256, 0, stream>>>(src, dst, rowptr, cursor, csrc, E);
  k_init<<<(N * HID + 255) / 256, 256, 0, stream>>>(m, h, hb, N);

  for (int s = 0; s < TSTEPS; ++s) {
    k_gather<<<(N + 3) / 4, 256, 0, stream>>>(rowptr, csrc, hb, hs16, N);
    k_gru<<<N / 16, 512, 0, stream>>>(hs16, h, hb, Wcomb, Whh16, bvec, b_ih, b_hh, deg, N);
  }

  hipMemsetAsync(hg, 0, (size_t)G * HID * 4, stream);
  hipMemsetAsync(cnt, 0, (size_t)G * 4, stream);
  k_cnt<<<(N + 255) / 256, 256, 0, stream>>>(gid, cnt, N);
  k_pool<<<(N + 499) / 500, HID, 0, stream>>>(h, gid, hg, N);
  k_cls<<<1, 640, 0, stream>>>(hg, cnt, W_cls, b_cls, out, G);
}

// Round 3
// 1906.280 us; speedup vs baseline: 16.4247x; 1.3110x over previous
//
#include <hip/hip_runtime.h>

#define HID 128
#define G3  384   // 3*HID
#define TSTEPS 5

typedef unsigned int  uint;
typedef unsigned short ushort;

typedef float  f32x4  __attribute__((ext_vector_type(4)));
typedef __bf16 bf16x8 __attribute__((ext_vector_type(8)));

union B8u { uint4 u; bf16x8 b; ushort s[8]; };

static __device__ inline ushort f2bf(float f) {
  uint u = __float_as_uint(f);
  uint r = u + 0x7fffu + ((u >> 16) & 1u);   // RTN-even
  return (ushort)(r >> 16);
}
static __device__ inline float bf2f(ushort s) {
  return __uint_as_float(((uint)s) << 16);
}

// ---- once per call: W_comb = W_ih @ W_e (bf16), bvec = W_ih @ b_e, W_hh -> bf16
__global__ __launch_bounds__(128) void k_weights(
    const float* __restrict__ W_e, const float* __restrict__ b_e,
    const float* __restrict__ W_ih, const float* __restrict__ W_hh,
    ushort* __restrict__ Wcomb, ushort* __restrict__ Whh16, float* __restrict__ bvec)
{
  int j = blockIdx.x, t = threadIdx.x;
  if (j < G3) {
    __shared__ float row[HID];
    row[t] = W_ih[j * HID + t];
    __syncthreads();
    float acc = 0.f;
    for (int k = 0; k < HID; ++k) acc = fmaf(row[k], W_e[k * HID + t], acc);
    Wcomb[j * HID + t] = f2bf(acc);
    if (t == 0) {
      float b = 0.f;
      for (int k = 0; k < HID; ++k) b += row[k] * b_e[k];
      bvec[j] = b;
    }
  } else {
    int j2 = j - G3;
    Whh16[j2 * HID + t] = f2bf(W_hh[j2 * HID + t]);
  }
}

__global__ void k_deg(const int* __restrict__ dst, int* __restrict__ deg, int E) {
  int e = blockIdx.x * 256 + threadIdx.x;
  if (e < E) atomicAdd(&deg[dst[e]], 1);
}

// single-block exclusive scan of deg -> rowptr
__global__ __launch_bounds__(1024) void k_scan(const int* __restrict__ deg,
                                               int* __restrict__ rowptr, int N) {
  __shared__ int part[1024];
  int t = threadIdx.x;
  int chunk = (N + 1023) / 1024;
  int b = t * chunk, e = min(b + chunk, N);
  if (b > N) { b = N; }
  int s = 0;
  for (int i = b; i < e; ++i) s += deg[i];
  part[t] = s;
  __syncthreads();
  for (int off = 1; off < 1024; off <<= 1) {
    int x = (t >= off) ? part[t - off] : 0;
    __syncthreads();
    part[t] += x;
    __syncthreads();
  }
  int run = part[t] - s;   // exclusive prefix for this chunk
  for (int i = b; i < e; ++i) { rowptr[i] = run; run += deg[i]; }
  if (t == 1023) rowptr[N] = part[1023];
}

__global__ void k_fill(const int* __restrict__ src, const int* __restrict__ dst,
                       const int* __restrict__ rowptr, int* __restrict__ cursor,
                       int* __restrict__ csrc, int E) {
  int e = blockIdx.x * 256 + threadIdx.x;
  if (e >= E) return;
  int d = dst[e];
  int p = atomicAdd(&cursor[d], 1);
  csrc[rowptr[d] + p] = src[e];
}

__global__ void k_init(const float* __restrict__ m, float* __restrict__ h,
                       ushort* __restrict__ hb, int N) {
  int idx = blockIdx.x * 256 + threadIdx.x;
  if (idx >= N * HID) return;
  int d = idx & (HID - 1);
  float v = (d == 0) ? m[idx >> 7] : 0.f;
  h[idx] = v;
  hb[idx] = f2bf(v);
}

// ---- gather: hs16[v] = bf16( sum_{u in N_in(v)} h[u] ); one wave per node,
// lane owns 2 dims (dword = 2 bf16), fp32 accumulate, 2x unroll for MLP
__global__ __launch_bounds__(256) void k_gather(
    const int* __restrict__ rowptr, const int* __restrict__ csrc,
    const ushort* __restrict__ hb, ushort* __restrict__ hs16, int N)
{
  int v = blockIdx.x * 4 + (threadIdx.x >> 6);
  if (v >= N) return;
  int lane = threadIdx.x & 63;
  int beg = rowptr[v], end = rowptr[v + 1];
  float a0 = 0.f, a1 = 0.f, b0 = 0.f, b1 = 0.f;
  int e = beg;
  for (; e + 1 < end; e += 2) {
    int s0 = csrc[e], s1 = csrc[e + 1];
    uint w0 = *(const uint*)(hb + (size_t)s0 * HID + lane * 2);
    uint w1 = *(const uint*)(hb + (size_t)s1 * HID + lane * 2);
    a0 += bf2f((ushort)w0); a1 += bf2f((ushort)(w0 >> 16));
    b0 += bf2f((ushort)w1); b1 += bf2f((ushort)(w1 >> 16));
  }
  if (e < end) {
    int s0 = csrc[e];
    uint w0 = *(const uint*)(hb + (size_t)s0 * HID + lane * 2);
    a0 += bf2f((ushort)w0); a1 += bf2f((ushort)(w0 >> 16));
  }
  a0 += b0; a1 += b1;
  uint o = ((uint)f2bf(a1) << 16) | (uint)f2bf(a0);
  *(uint*)(hs16 + (size_t)v * HID + lane * 2) = o;
}

// ---- fused GEMM (gi from hs16 via Wcomb, gh from hb via Whh) + GRU, in-place h
// block = 512 thr (8 waves) over a 16-node strip; wave w owns dims [16w,16w+16)
__global__ __launch_bounds__(512) void k_gru(
    const ushort* __restrict__ hsum16, float* h, ushort* hb,
    const ushort* __restrict__ Wcomb, const ushort* __restrict__ Whh16,
    const float* __restrict__ bvec, const float* __restrict__ b_ih,
    const float* __restrict__ b_hh, const int* __restrict__ deg, int N)
{
  const int n0 = blockIdx.x * 16;
  const int w = threadIdx.x >> 6;
  const int lane = threadIdx.x & 63;
  const int quad = lane >> 4, l16 = lane & 15;
  const int d0 = w * 16;
  const size_t arow = (size_t)(n0 + l16) * HID;

  f32x4 acc[6] = {};   // 0..2: gi r/z/n tiles, 3..5: gh r/z/n tiles
#pragma unroll
  for (int kc = 0; kc < 4; ++kc) {
    int klane = kc * 32 + quad * 8;
    B8u af; af.u = *(const uint4*)(hsum16 + arow + klane);  // A = hsum (bf16)
    B8u hf; hf.u = *(const uint4*)(hb + arow + klane);      // A = h    (bf16)
#pragma unroll
    for (int g = 0; g < 3; ++g) {
      int j = (d0 + g * 128 + l16) * HID + klane;
      B8u bw; bw.u = *(const uint4*)(Wcomb + j);
      acc[g] = __builtin_amdgcn_mfma_f32_16x16x32_bf16(af.b, bw.b, acc[g], 0, 0, 0);
      B8u bh; bh.u = *(const uint4*)(Whh16 + j);
      acc[3 + g] = __builtin_amdgcn_mfma_f32_16x16x32_bf16(hf.b, bh.b, acc[3 + g], 0, 0, 0);
    }
  }

  const int d = d0 + l16;
  const float bir = b_ih[d], biz = b_ih[d + 128], bin_ = b_ih[d + 256];
  const float bhr = b_hh[d], bhz = b_hh[d + 128], bhn = b_hh[d + 256];
  const float vr = bvec[d], vz = bvec[d + 128], vn = bvec[d + 256];

  float hold[4], degf[4];
#pragma unroll
  for (int rg = 0; rg < 4; ++rg) {
    int n = n0 + quad * 4 + rg;
    hold[rg] = h[(size_t)n * HID + d];
    degf[rg] = (float)deg[n];
  }
  __syncthreads();   // all reads of h/hb done before in-place writes
#pragma unroll
  for (int rg = 0; rg < 4; ++rg) {
    float ir = acc[0][rg] + degf[rg] * vr + bir;
    float iz = acc[1][rg] + degf[rg] * vz + biz;
    float in_ = acc[2][rg] + degf[rg] * vn + bin_;
    float hr = acc[3][rg] + bhr;
    float hz = acc[4][rg] + bhz;
    float hn = acc[5][rg] + bhn;
    float r = 1.f / (1.f + __expf(-(ir + hr)));
    float z = 1.f / (1.f + __expf(-(iz + hz)));
    float x2 = in_ + r * hn;
    float e2 = __expf(2.f * x2);
    float nv = 1.f - 2.f / (e2 + 1.f);   // tanh
    float hv = (1.f - z) * nv + z * hold[rg];
    size_t o = (size_t)(n0 + quad * 4 + rg) * HID + d;
    h[o] = hv;
    hb[o] = f2bf(hv);
  }
}

// ---- per-graph counts from SORTED gid: binary search, no atomics
__global__ __launch_bounds__(64) void k_bounds(const int* __restrict__ gid,
                                               int* __restrict__ cnt, int N, int G) {
  int g = threadIdx.x;
  if (g >= G) return;
  // lower_bound(g) and lower_bound(g+1)
  int lo = 0, hi = N;
  while (lo < hi) { int mid = (lo + hi) >> 1; if (gid[mid] < g) lo = mid + 1; else hi = mid; }
  int lb0 = lo;
  lo = 0; hi = N;
  int g1 = g + 1;
  while (lo < hi) { int mid = (lo + hi) >> 1; if (gid[mid] < g1) lo = mid + 1; else hi = mid; }
  cnt[g] = lo - lb0;
}

// ---- pooling: graph_ids sorted -> run-length accumulate, few atomics
#define POOL_CHUNK 160
__global__ __launch_bounds__(128) void k_pool(const float* __restrict__ h,
                                              const int* __restrict__ gid,
                                              float* __restrict__ hg, int N) {
  int d = threadIdx.x;
  int start = blockIdx.x * POOL_CHUNK;
  if (start >= N) return;
  int end = min(start + POOL_CHUNK, N);
  float acc = 0.f;
  int g = gid[start];
  for (int n = start; n < end; ++n) {
    int gn = gid[n];
    if (gn != g) { unsafeAtomicAdd(&hg[g * HID + d], acc); acc = 0.f; g = gn; }
    acc += fmaxf(h[(size_t)n * HID + d], 0.f);   // relu
  }
  unsafeAtomicAdd(&hg[g * HID + d], acc);
}

__global__ __launch_bounds__(640) void k_cls(const float* __restrict__ hg,
                                             const int* __restrict__ cnt,
                                             const float* __restrict__ Wc,
                                             const float* __restrict__ bc,
                                             float* __restrict__ out, int G) {
  int t = threadIdx.x;
  if (t >= G * 10) return;
  int g = t / 10, c = t % 10;
  float inv = 1.f / fmaxf((float)cnt[g], 1.f);
  float acc = 0.f;
  for (int d = 0; d < HID; ++d) acc = fmaf(hg[g * HID + d], Wc[c * HID + d], acc);
  out[t] = acc * inv + bc[c];
}

extern "C" void kernel_launch(void* const* d_in, const int* in_sizes, int n_in,
                              void* d_out, int out_size, void* d_ws, size_t ws_size,
                              hipStream_t stream) {
  const int N = in_sizes[0];
  const int E = in_sizes[9];
  const float* m    = (const float*)d_in[0];
  const float* W_e  = (const float*)d_in[1];
  const float* b_e  = (const float*)d_in[2];
  const float* W_ih = (const float*)d_in[3];
  const float* b_ih = (const float*)d_in[4];
  const float* W_hh = (const float*)d_in[5];
  const float* b_hh = (const float*)d_in[6];
  const float* W_cls = (const float*)d_in[7];
  const float* b_cls = (const float*)d_in[8];
  const int* src = (const int*)d_in[9];
  const int* dst = (const int*)d_in[10];
  const int* gid = (const int*)d_in[11];
  const int G = out_size / 10;
  float* out = (float*)d_out;

  size_t off = 0;
  auto alloc = [&](size_t b) {
    char* p = (char*)d_ws + off;
    off += (b + 255) & ~(size_t)255;
    return (void*)p;
  };
  float*  h      = (float*) alloc((size_t)N * HID * 4);
  ushort* hb     = (ushort*)alloc((size_t)N * HID * 2);
  ushort* hs16   = (ushort*)alloc((size_t)N * HID * 2);
  int*    deg    = (int*)   alloc((size_t)N * 4);
  int*    rowptr = (int*)   alloc((size_t)(N + 1) * 4);
  int*    cursor = (int*)   alloc((size_t)N * 4);
  int*    csrc   = (int*)   alloc((size_t)E * 4);
  ushort* Wcomb  = (ushort*)alloc((size_t)G3 * HID * 2);
  ushort* Whh16  = (ushort*)alloc((size_t)G3 * HID * 2);
  float*  bvec   = (float*) alloc((size_t)G3 * 4);
  float*  hg     = (float*) alloc((size_t)G * HID * 4);
  int*    cnt    = (int*)   alloc((size_t)G * 4);
  if (off > ws_size) return;   // workspace too small -> visible failure

  k_weights<<<2 * G3, HID, 0, stream>>>(W_e, b_e, W_ih, W_hh, Wcomb, Whh16, bvec);
  hipMemsetAsync(deg, 0, (size_t)N * 4, stream);
  hipMemsetAsync(cursor, 0, (size_t)N * 4, stream);
  k_deg<<<(E + 255) / 256, 256, 0, stream>>>(dst, deg, E);
  k_scan<<<1, 1024, 0, stream>>>(deg, rowptr, N);
  k_fill<<<(E + 255) / 256, 256, 0, stream>>>(src, dst, rowptr, cursor, csrc, E);
  k_init<<<(N * HID + 255) / 256, 256, 0, stream>>>(m, h, hb, N);

  for (int s = 0; s < TSTEPS; ++s) {
    k_gather<<<(N + 3) / 4, 256, 0, stream>>>(rowptr, csrc, hb, hs16, N);
    k_gru<<<N / 16, 512, 0, stream>>>(hs16, h, hb, Wcomb, Whh16, bvec, b_ih, b_hh, deg, N);
  }

  hipMemsetAsync(hg, 0, (size_t)G * HID * 4, stream);
  k_bounds<<<1, 64, 0, stream>>>(gid, cnt, N, G);
  k_pool<<<(N + POOL_CHUNK - 1) / POOL_CHUNK, HID, 0, stream>>>(h, gid, hg, N);
  k_cls<<<1, 640, 0, stream>>>(hg, cnt, W_cls, b_cls, out, G);
}

// Round 4
// 1279.685 us; speedup vs baseline: 24.4671x; 1.4896x over previous
//
#include <hip/hip_runtime.h>

#define HID 128
#define G3  384   // 3*HID
#define TSTEPS 5

typedef unsigned int  uint;
typedef unsigned short ushort;

typedef float  f32x4  __attribute__((ext_vector_type(4)));
typedef __bf16 bf16x8 __attribute__((ext_vector_type(8)));

union B8u { uint4 u; bf16x8 b; ushort s[8]; };

static __device__ inline ushort f2bf(float f) {
  uint u = __float_as_uint(f);
  uint r = u + 0x7fffu + ((u >> 16) & 1u);   // RTN-even
  return (ushort)(r >> 16);
}
static __device__ inline float bf2f(ushort s) {
  return __uint_as_float(((uint)s) << 16);
}

// ---- once per call: W_comb = W_ih @ W_e (bf16), bvec = W_ih @ b_e, W_hh -> bf16
__global__ __launch_bounds__(128) void k_weights(
    const float* __restrict__ W_e, const float* __restrict__ b_e,
    const float* __restrict__ W_ih, const float* __restrict__ W_hh,
    ushort* __restrict__ Wcomb, ushort* __restrict__ Whh16, float* __restrict__ bvec)
{
  int j = blockIdx.x, t = threadIdx.x;
  if (j < G3) {
    __shared__ float row[HID];
    row[t] = W_ih[j * HID + t];
    __syncthreads();
    float acc = 0.f;
    for (int k = 0; k < HID; ++k) acc = fmaf(row[k], W_e[k * HID + t], acc);
    Wcomb[j * HID + t] = f2bf(acc);
    if (t == 0) {
      float b = 0.f;
      for (int k = 0; k < HID; ++k) b += row[k] * b_e[k];
      bvec[j] = b;
    }
  } else {
    int j2 = j - G3;
    Whh16[j2 * HID + t] = f2bf(W_hh[j2 * HID + t]);
  }
}

__global__ void k_deg(const int* __restrict__ dst, int* __restrict__ deg, int E) {
  int e = blockIdx.x * 256 + threadIdx.x;
  if (e < E) atomicAdd(&deg[dst[e]], 1);
}

// single-block exclusive scan of deg -> rowptr
__global__ __launch_bounds__(1024) void k_scan(const int* __restrict__ deg,
                                               int* __restrict__ rowptr, int N) {
  __shared__ int part[1024];
  int t = threadIdx.x;
  int chunk = (N + 1023) / 1024;
  int b = t * chunk, e = min(b + chunk, N);
  if (b > N) { b = N; }
  int s = 0;
  for (int i = b; i < e; ++i) s += deg[i];
  part[t] = s;
  __syncthreads();
  for (int off = 1; off < 1024; off <<= 1) {
    int x = (t >= off) ? part[t - off] : 0;
    __syncthreads();
    part[t] += x;
    __syncthreads();
  }
  int run = part[t] - s;   // exclusive prefix for this chunk
  for (int i = b; i < e; ++i) { rowptr[i] = run; run += deg[i]; }
  if (t == 1023) rowptr[N] = part[1023];
}

__global__ void k_fill(const int* __restrict__ src, const int* __restrict__ dst,
                       const int* __restrict__ rowptr, int* __restrict__ cursor,
                       int* __restrict__ csrc, int E) {
  int e = blockIdx.x * 256 + threadIdx.x;
  if (e >= E) return;
  int d = dst[e];
  int p = atomicAdd(&cursor[d], 1);
  csrc[rowptr[d] + p] = src[e];
}

__global__ void k_init(const float* __restrict__ m, float* __restrict__ h,
                       ushort* __restrict__ hb, int N) {
  int idx = blockIdx.x * 256 + threadIdx.x;
  if (idx >= N * HID) return;
  int d = idx & (HID - 1);
  float v = (d == 0) ? m[idx >> 7] : 0.f;
  h[idx] = v;
  hb[idx] = f2bf(v);
}

// ---- gather: hs16[v] = bf16( sum_{u in N_in(v)} h[u] ); one wave per node,
// lane owns 2 dims (dword = 2 bf16), fp32 accumulate, 4x unroll for MLP
__global__ __launch_bounds__(256) void k_gather(
    const int* __restrict__ rowptr, const int* __restrict__ csrc,
    const ushort* __restrict__ hb, ushort* __restrict__ hs16, int N)
{
  int v = blockIdx.x * 4 + (threadIdx.x >> 6);
  if (v >= N) return;
  int lane = threadIdx.x & 63;
  int beg = rowptr[v], end = rowptr[v + 1];
  float a0 = 0.f, a1 = 0.f, b0 = 0.f, b1 = 0.f;
  float c0 = 0.f, c1 = 0.f, d0 = 0.f, d1 = 0.f;
  int e = beg;
  for (; e + 3 < end; e += 4) {
    int s0 = csrc[e], s1 = csrc[e + 1], s2 = csrc[e + 2], s3 = csrc[e + 3];
    uint w0 = *(const uint*)(hb + (size_t)s0 * HID + lane * 2);
    uint w1 = *(const uint*)(hb + (size_t)s1 * HID + lane * 2);
    uint w2 = *(const uint*)(hb + (size_t)s2 * HID + lane * 2);
    uint w3 = *(const uint*)(hb + (size_t)s3 * HID + lane * 2);
    a0 += bf2f((ushort)w0); a1 += bf2f((ushort)(w0 >> 16));
    b0 += bf2f((ushort)w1); b1 += bf2f((ushort)(w1 >> 16));
    c0 += bf2f((ushort)w2); c1 += bf2f((ushort)(w2 >> 16));
    d0 += bf2f((ushort)w3); d1 += bf2f((ushort)(w3 >> 16));
  }
  for (; e < end; ++e) {
    int s0 = csrc[e];
    uint w0 = *(const uint*)(hb + (size_t)s0 * HID + lane * 2);
    a0 += bf2f((ushort)w0); a1 += bf2f((ushort)(w0 >> 16));
  }
  a0 += b0 + c0 + d0; a1 += b1 + c1 + d1;
  uint o = ((uint)f2bf(a1) << 16) | (uint)f2bf(a0);
  *(uint*)(hs16 + (size_t)v * HID + lane * 2) = o;
}

// ---- fused GEMM + GRU. Weights live in VGPRs for the whole kernel; block
// grid-strides over 16-node strips with manual double-buffered A/epilogue
// loads. hb is ping-ponged across steps (hbc -> hbn) so NO barriers needed;
// h fp32 updated in place (each (n,d) element touched by exactly one lane).
__global__ __launch_bounds__(512, 2) void k_gru(
    const ushort* __restrict__ hs16, float* __restrict__ h,
    const ushort* __restrict__ hbc, ushort* __restrict__ hbn,
    const ushort* __restrict__ Wcomb, const ushort* __restrict__ Whh16,
    const float* __restrict__ bvec, const float* __restrict__ b_ih,
    const float* __restrict__ b_hh, const int* __restrict__ deg, int N)
{
  const int w = threadIdx.x >> 6;
  const int lane = threadIdx.x & 63;
  const int quad = lane >> 4, l16 = lane & 15;
  const int d0 = w * 16;
  const int d = d0 + l16;

  // persistent weight fragments: 24 x uint4 = 96 VGPRs
  B8u bw[3][4], bh[3][4];
#pragma unroll
  for (int g = 0; g < 3; ++g)
#pragma unroll
    for (int kc = 0; kc < 4; ++kc) {
      int j = (d0 + g * 128 + l16) * HID + kc * 32 + quad * 8;
      bw[g][kc].u = *(const uint4*)(Wcomb + j);
      bh[g][kc].u = *(const uint4*)(Whh16 + j);
    }
  const float bir = b_ih[d], biz = b_ih[d + 128], bin_ = b_ih[d + 256];
  const float bhr = b_hh[d], bhz = b_hh[d + 128], bhn = b_hh[d + 256];
  const float vr = bvec[d], vz = bvec[d + 128], vn = bvec[d + 256];

  const int nstrip = N >> 4;
  int s = blockIdx.x;
  if (s >= nstrip) return;

  B8u af[4], hf[4]; float hold[4], degf[4];
  {
    int n0 = s << 4;
    size_t arow = (size_t)(n0 + l16) * HID + quad * 8;
#pragma unroll
    for (int kc = 0; kc < 4; ++kc) {
      af[kc].u = *(const uint4*)(hs16 + arow + kc * 32);
      hf[kc].u = *(const uint4*)(hbc + arow + kc * 32);
    }
#pragma unroll
    for (int rg = 0; rg < 4; ++rg) {
      int n = n0 + quad * 4 + rg;
      hold[rg] = h[(size_t)n * HID + d];
      degf[rg] = (float)deg[n];
    }
  }

  while (true) {
    int ns = s + (int)gridDim.x;
    bool more = ns < nstrip;
    B8u af2[4], hf2[4]; float hold2[4], degf2[4];
    if (more) {   // prefetch next strip while computing current
      int n0 = ns << 4;
      size_t arow = (size_t)(n0 + l16) * HID + quad * 8;
#pragma unroll
      for (int kc = 0; kc < 4; ++kc) {
        af2[kc].u = *(const uint4*)(hs16 + arow + kc * 32);
        hf2[kc].u = *(const uint4*)(hbc + arow + kc * 32);
      }
#pragma unroll
      for (int rg = 0; rg < 4; ++rg) {
        int n = n0 + quad * 4 + rg;
        hold2[rg] = h[(size_t)n * HID + d];
        degf2[rg] = (float)deg[n];
      }
    }

    f32x4 acc[6] = {};
#pragma unroll
    for (int kc = 0; kc < 4; ++kc)
#pragma unroll
      for (int g = 0; g < 3; ++g) {
        acc[g]     = __builtin_amdgcn_mfma_f32_16x16x32_bf16(af[kc].b, bw[g][kc].b, acc[g], 0, 0, 0);
        acc[3 + g] = __builtin_amdgcn_mfma_f32_16x16x32_bf16(hf[kc].b, bh[g][kc].b, acc[3 + g], 0, 0, 0);
      }

    int n0 = s << 4;
#pragma unroll
    for (int rg = 0; rg < 4; ++rg) {
      float ir = acc[0][rg] + degf[rg] * vr + bir;
      float iz = acc[1][rg] + degf[rg] * vz + biz;
      float in_ = acc[2][rg] + degf[rg] * vn + bin_;
      float hr = acc[3][rg] + bhr;
      float hz = acc[4][rg] + bhz;
      float hn = acc[5][rg] + bhn;
      float r = 1.f / (1.f + __expf(-(ir + hr)));
      float z = 1.f / (1.f + __expf(-(iz + hz)));
      float x2 = in_ + r * hn;
      float e2 = __expf(2.f * x2);
      float nv = 1.f - 2.f / (e2 + 1.f);   // tanh
      float hv = (1.f - z) * nv + z * hold[rg];
      size_t o = (size_t)(n0 + quad * 4 + rg) * HID + d;
      h[o] = hv;
      hbn[o] = f2bf(hv);
    }

    if (!more) break;
    s = ns;
#pragma unroll
    for (int kc = 0; kc < 4; ++kc) { af[kc] = af2[kc]; hf[kc] = hf2[kc]; }
#pragma unroll
    for (int rg = 0; rg < 4; ++rg) { hold[rg] = hold2[rg]; degf[rg] = degf2[rg]; }
  }
}

// ---- per-graph counts from SORTED gid: binary search, no atomics
__global__ __launch_bounds__(64) void k_bounds(const int* __restrict__ gid,
                                               int* __restrict__ cnt, int N, int G) {
  int g = threadIdx.x;
  if (g >= G) return;
  int lo = 0, hi = N;
  while (lo < hi) { int mid = (lo + hi) >> 1; if (gid[mid] < g) lo = mid + 1; else hi = mid; }
  int lb0 = lo;
  lo = 0; hi = N;
  int g1 = g + 1;
  while (lo < hi) { int mid = (lo + hi) >> 1; if (gid[mid] < g1) lo = mid + 1; else hi = mid; }
  cnt[g] = lo - lb0;
}

// ---- pooling: graph_ids sorted -> run-length accumulate, few atomics
#define POOL_CHUNK 96
__global__ __launch_bounds__(128) void k_pool(const float* __restrict__ h,
                                              const int* __restrict__ gid,
                                              float* __restrict__ hg, int N) {
  int d = threadIdx.x;
  int start = blockIdx.x * POOL_CHUNK;
  if (start >= N) return;
  int end = min(start + POOL_CHUNK, N);
  float acc = 0.f;
  int g = gid[start];
  for (int n = start; n < end; ++n) {
    int gn = gid[n];
    if (gn != g) { unsafeAtomicAdd(&hg[g * HID + d], acc); acc = 0.f; g = gn; }
    acc += fmaxf(h[(size_t)n * HID + d], 0.f);   // relu
  }
  unsafeAtomicAdd(&hg[g * HID + d], acc);
}

__global__ __launch_bounds__(640) void k_cls(const float* __restrict__ hg,
                                             const int* __restrict__ cnt,
                                             const float* __restrict__ Wc,
                                             const float* __restrict__ bc,
                                             float* __restrict__ out, int G) {
  int t = threadIdx.x;
  if (t >= G * 10) return;
  int g = t / 10, c = t % 10;
  float inv = 1.f / fmaxf((float)cnt[g], 1.f);
  float acc = 0.f;
  for (int d = 0; d < HID; ++d) acc = fmaf(hg[g * HID + d], Wc[c * HID + d], acc);
  out[t] = acc * inv + bc[c];
}

extern "C" void kernel_launch(void* const* d_in, const int* in_sizes, int n_in,
                              void* d_out, int out_size, void* d_ws, size_t ws_size,
                              hipStream_t stream) {
  const int N = in_sizes[0];
  const int E = in_sizes[9];
  const float* m    = (const float*)d_in[0];
  const float* W_e  = (const float*)d_in[1];
  const float* b_e  = (const float*)d_in[2];
  const float* W_ih = (const float*)d_in[3];
  const float* b_ih = (const float*)d_in[4];
  const float* W_hh = (const float*)d_in[5];
  const float* b_hh = (const float*)d_in[6];
  const float* W_cls = (const float*)d_in[7];
  const float* b_cls = (const float*)d_in[8];
  const int* src = (const int*)d_in[9];
  const int* dst = (const int*)d_in[10];
  const int* gid = (const int*)d_in[11];
  const int G = out_size / 10;
  float* out = (float*)d_out;

  size_t off = 0;
  auto alloc = [&](size_t b) {
    char* p = (char*)d_ws + off;
    off += (b + 255) & ~(size_t)255;
    return (void*)p;
  };
  float*  h      = (float*) alloc((size_t)N * HID * 4);
  ushort* hb0    = (ushort*)alloc((size_t)N * HID * 2);
  ushort* hb1    = (ushort*)alloc((size_t)N * HID * 2);
  ushort* hs16   = (ushort*)alloc((size_t)N * HID * 2);
  int*    deg    = (int*)   alloc((size_t)N * 4);
  int*    rowptr = (int*)   alloc((size_t)(N + 1) * 4);
  int*    cursor = (int*)   alloc((size_t)N * 4);
  int*    csrc   = (int*)   alloc((size_t)E * 4);
  ushort* Wcomb  = (ushort*)alloc((size_t)G3 * HID * 2);
  ushort* Whh16  = (ushort*)alloc((size_t)G3 * HID * 2);
  float*  bvec   = (float*) alloc((size_t)G3 * 4);
  float*  hg     = (float*) alloc((size_t)G * HID * 4);
  int*    cnt    = (int*)   alloc((size_t)G * 4);
  if (off > ws_size) return;   // workspace too small -> visible failure

  k_weights<<<2 * G3, HID, 0, stream>>>(W_e, b_e, W_ih, W_hh, Wcomb, Whh16, bvec);
  hipMemsetAsync(deg, 0, (size_t)N * 4, stream);
  hipMemsetAsync(cursor, 0, (size_t)N * 4, stream);
  k_deg<<<(E + 255) / 256, 256, 0, stream>>>(dst, deg, E);
  k_scan<<<1, 1024, 0, stream>>>(deg, rowptr, N);
  k_fill<<<(E + 255) / 256, 256, 0, stream>>>(src, dst, rowptr, cursor, csrc, E);
  k_init<<<(N * HID + 255) / 256, 256, 0, stream>>>(m, h, hb0, N);

  ushort* hbc = hb0;
  ushort* hbn = hb1;
  for (int s = 0; s < TSTEPS; ++s) {
    k_gather<<<(N + 3) / 4, 256, 0, stream>>>(rowptr, csrc, hbc, hs16, N);
    int nstrip = N >> 4;
    int blocks = nstrip < 1024 ? nstrip : 1024;
    k_gru<<<blocks, 512, 0, stream>>>(hs16, h, hbc, hbn, Wcomb, Whh16, bvec, b_ih, b_hh, deg, N);
    ushort* t = hbc; hbc = hbn; hbn = t;
  }

  hipMemsetAsync(hg, 0, (size_t)G * HID * 4, stream);
  k_bounds<<<1, 64, 0, stream>>>(gid, cnt, N, G);
  k_pool<<<(N + POOL_CHUNK - 1) / POOL_CHUNK, HID, 0, stream>>>(h, gid, hg, N);
  k_cls<<<1, 640, 0, stream>>>(hg, cnt, W_cls, b_cls, out, G);
}

// Round 5
// 1137.601 us; speedup vs baseline: 27.5230x; 1.1249x over previous
//
#include <hip/hip_runtime.h>

#define HID 128
#define G3  384   // 3*HID
#define TSTEPS 5
#define SCAN_TILE 2048   // 256 thr * 8 elems

typedef unsigned int  uint;
typedef unsigned short ushort;

typedef float  f32x4  __attribute__((ext_vector_type(4)));
typedef __bf16 bf16x8 __attribute__((ext_vector_type(8)));

union B8u { uint4 u; bf16x8 b; ushort s[8]; };

static __device__ inline ushort f2bf(float f) {
  uint u = __float_as_uint(f);
  uint r = u + 0x7fffu + ((u >> 16) & 1u);   // RTN-even
  return (ushort)(r >> 16);
}
static __device__ inline float bf2f(ushort s) {
  return __uint_as_float(((uint)s) << 16);
}

// ---- once per call: W_comb = W_ih @ W_e (bf16), bvec = W_ih @ b_e, W_hh -> bf16
__global__ __launch_bounds__(128) void k_weights(
    const float* __restrict__ W_e, const float* __restrict__ b_e,
    const float* __restrict__ W_ih, const float* __restrict__ W_hh,
    ushort* __restrict__ Wcomb, ushort* __restrict__ Whh16, float* __restrict__ bvec)
{
  int j = blockIdx.x, t = threadIdx.x;
  if (j < G3) {
    __shared__ float row[HID];
    row[t] = W_ih[j * HID + t];
    __syncthreads();
    float acc = 0.f;
    for (int k = 0; k < HID; ++k) acc = fmaf(row[k], W_e[k * HID + t], acc);
    Wcomb[j * HID + t] = f2bf(acc);
    if (t == 0) {
      float b = 0.f;
      for (int k = 0; k < HID; ++k) b += row[k] * b_e[k];
      bvec[j] = b;
    }
  } else {
    int j2 = j - G3;
    Whh16[j2 * HID + t] = f2bf(W_hh[j2 * HID + t]);
  }
}

__global__ void k_deg(const int* __restrict__ dst, int* __restrict__ deg, int E) {
  int e = blockIdx.x * 256 + threadIdx.x;
  if (e < E) atomicAdd(&deg[dst[e]], 1);
}

// ---- 3-phase hierarchical scan of deg -> rowptr (exclusive), rowptr[N]=total
__global__ __launch_bounds__(256) void k_scan1(const int* __restrict__ deg,
                                               int* __restrict__ bsum, int N) {
  int base = blockIdx.x * SCAN_TILE + threadIdx.x * 8;
  int s = 0;
#pragma unroll
  for (int i = 0; i < 8; ++i) { int idx = base + i; if (idx < N) s += deg[idx]; }
  int lane = threadIdx.x & 63;
#pragma unroll
  for (int off = 32; off > 0; off >>= 1) s += __shfl_down(s, off, 64);
  __shared__ int ws[4];
  if (lane == 0) ws[threadIdx.x >> 6] = s;
  __syncthreads();
  if (threadIdx.x == 0) bsum[blockIdx.x] = ws[0] + ws[1] + ws[2] + ws[3];
}

__global__ __launch_bounds__(64) void k_scan2(const int* __restrict__ bsum,
                                              int* __restrict__ boff,
                                              int* __restrict__ rowptr, int B, int N) {
  int t = threadIdx.x;
  int orig = (t < B) ? bsum[t] : 0;
  int v = orig;
#pragma unroll
  for (int off = 1; off < 64; off <<= 1) {
    int u = __shfl_up(v, off, 64);
    if (t >= off) v += u;
  }
  if (t < B) boff[t] = v - orig;
  if (t == B - 1) rowptr[N] = v;   // total
}

__global__ __launch_bounds__(256) void k_scan3(const int* __restrict__ deg,
                                               const int* __restrict__ boff,
                                               int* __restrict__ rowptr, int N) {
  int base = blockIdx.x * SCAN_TILE + threadIdx.x * 8;
  int x[8]; int s = 0;
#pragma unroll
  for (int i = 0; i < 8; ++i) { int idx = base + i; x[i] = (idx < N) ? deg[idx] : 0; s += x[i]; }
  int lane = threadIdx.x & 63, wv = threadIdx.x >> 6;
  int incl = s;
#pragma unroll
  for (int off = 1; off < 64; off <<= 1) {
    int u = __shfl_up(incl, off, 64);
    if (lane >= off) incl += u;
  }
  __shared__ int wsum[4];
  if (lane == 63) wsum[wv] = incl;
  __syncthreads();
  int wbase = 0;
  for (int i = 0; i < wv; ++i) wbase += wsum[i];
  int run = boff[blockIdx.x] + wbase + (incl - s);
#pragma unroll
  for (int i = 0; i < 8; ++i) { int idx = base + i; if (idx < N) rowptr[idx] = run; run += x[i]; }
}

// fallback single-block scan (only if N > 64*SCAN_TILE)
__global__ __launch_bounds__(1024) void k_scan(const int* __restrict__ deg,
                                               int* __restrict__ rowptr, int N) {
  __shared__ int part[1024];
  int t = threadIdx.x;
  int chunk = (N + 1023) / 1024;
  int b = t * chunk, e = min(b + chunk, N);
  if (b > N) { b = N; }
  int s = 0;
  for (int i = b; i < e; ++i) s += deg[i];
  part[t] = s;
  __syncthreads();
  for (int off = 1; off < 1024; off <<= 1) {
    int x = (t >= off) ? part[t - off] : 0;
    __syncthreads();
    part[t] += x;
    __syncthreads();
  }
  int run = part[t] - s;
  for (int i = b; i < e; ++i) { rowptr[i] = run; run += deg[i]; }
  if (t == 1023) rowptr[N] = part[1023];
}

__global__ void k_fill(const int* __restrict__ src, const int* __restrict__ dst,
                       const int* __restrict__ rowptr, int* __restrict__ cursor,
                       int* __restrict__ csrc, int E) {
  int e = blockIdx.x * 256 + threadIdx.x;
  if (e >= E) return;
  int d = dst[e];
  int p = atomicAdd(&cursor[d], 1);
  csrc[rowptr[d] + p] = src[e];
}

__global__ void k_init(const float* __restrict__ m, float* __restrict__ h,
                       ushort* __restrict__ hb, int N) {
  int idx = blockIdx.x * 256 + threadIdx.x;
  if (idx >= N * HID) return;
  int d = idx & (HID - 1);
  float v = (d == 0) ? m[idx >> 7] : 0.f;
  h[idx] = v;
  hb[idx] = f2bf(v);
}

// ---- gather: hs16[v] = bf16( sum_{u in N_in(v)} h[u] ); one wave per node,
// lane owns 2 dims (dword = 2 bf16), fp32 accumulate, 4x unroll for MLP
__global__ __launch_bounds__(256) void k_gather(
    const int* __restrict__ rowptr, const int* __restrict__ csrc,
    const ushort* __restrict__ hb, ushort* __restrict__ hs16, int N)
{
  int v = blockIdx.x * 4 + (threadIdx.x >> 6);
  if (v >= N) return;
  int lane = threadIdx.x & 63;
  int beg = rowptr[v], end = rowptr[v + 1];
  float a0 = 0.f, a1 = 0.f, b0 = 0.f, b1 = 0.f;
  float c0 = 0.f, c1 = 0.f, d0 = 0.f, d1 = 0.f;
  int e = beg;
  for (; e + 3 < end; e += 4) {
    int s0 = csrc[e], s1 = csrc[e + 1], s2 = csrc[e + 2], s3 = csrc[e + 3];
    uint w0 = *(const uint*)(hb + (size_t)s0 * HID + lane * 2);
    uint w1 = *(const uint*)(hb + (size_t)s1 * HID + lane * 2);
    uint w2 = *(const uint*)(hb + (size_t)s2 * HID + lane * 2);
    uint w3 = *(const uint*)(hb + (size_t)s3 * HID + lane * 2);
    a0 += bf2f((ushort)w0); a1 += bf2f((ushort)(w0 >> 16));
    b0 += bf2f((ushort)w1); b1 += bf2f((ushort)(w1 >> 16));
    c0 += bf2f((ushort)w2); c1 += bf2f((ushort)(w2 >> 16));
    d0 += bf2f((ushort)w3); d1 += bf2f((ushort)(w3 >> 16));
  }
  for (; e < end; ++e) {
    int s0 = csrc[e];
    uint w0 = *(const uint*)(hb + (size_t)s0 * HID + lane * 2);
    a0 += bf2f((ushort)w0); a1 += bf2f((ushort)(w0 >> 16));
  }
  a0 += b0 + c0 + d0; a1 += b1 + c1 + d1;
  uint o = ((uint)f2bf(a1) << 16) | (uint)f2bf(a0);
  *(uint*)(hs16 + (size_t)v * HID + lane * 2) = o;
}

// ---- fused GEMM + GRU. Weights live in VGPRs for the whole kernel; block
// grid-strides over 16-node strips with manual double-buffered A/epilogue
// loads. hb ping-pongs across steps (no barriers); h fp32 in place.
__global__ __launch_bounds__(512, 2) void k_gru(
    const ushort* __restrict__ hs16, float* __restrict__ h,
    const ushort* __restrict__ hbc, ushort* __restrict__ hbn,
    const ushort* __restrict__ Wcomb, const ushort* __restrict__ Whh16,
    const float* __restrict__ bvec, const float* __restrict__ b_ih,
    const float* __restrict__ b_hh, const int* __restrict__ deg, int N)
{
  const int w = threadIdx.x >> 6;
  const int lane = threadIdx.x & 63;
  const int quad = lane >> 4, l16 = lane & 15;
  const int d0 = w * 16;
  const int d = d0 + l16;

  B8u bw[3][4], bh[3][4];
#pragma unroll
  for (int g = 0; g < 3; ++g)
#pragma unroll
    for (int kc = 0; kc < 4; ++kc) {
      int j = (d0 + g * 128 + l16) * HID + kc * 32 + quad * 8;
      bw[g][kc].u = *(const uint4*)(Wcomb + j);
      bh[g][kc].u = *(const uint4*)(Whh16 + j);
    }
  const float bir = b_ih[d], biz = b_ih[d + 128], bin_ = b_ih[d + 256];
  const float bhr = b_hh[d], bhz = b_hh[d + 128], bhn = b_hh[d + 256];
  const float vr = bvec[d], vz = bvec[d + 128], vn = bvec[d + 256];

  const int nstrip = N >> 4;
  int s = blockIdx.x;
  if (s >= nstrip) return;

  B8u af[4], hf[4]; float hold[4], degf[4];
  {
    int n0 = s << 4;
    size_t arow = (size_t)(n0 + l16) * HID + quad * 8;
#pragma unroll
    for (int kc = 0; kc < 4; ++kc) {
      af[kc].u = *(const uint4*)(hs16 + arow + kc * 32);
      hf[kc].u = *(const uint4*)(hbc + arow + kc * 32);
    }
#pragma unroll
    for (int rg = 0; rg < 4; ++rg) {
      int n = n0 + quad * 4 + rg;
      hold[rg] = h[(size_t)n * HID + d];
      degf[rg] = (float)deg[n];
    }
  }

  while (true) {
    int ns = s + (int)gridDim.x;
    bool more = ns < nstrip;
    B8u af2[4], hf2[4]; float hold2[4], degf2[4];
    if (more) {
      int n0 = ns << 4;
      size_t arow = (size_t)(n0 + l16) * HID + quad * 8;
#pragma unroll
      for (int kc = 0; kc < 4; ++kc) {
        af2[kc].u = *(const uint4*)(hs16 + arow + kc * 32);
        hf2[kc].u = *(const uint4*)(hbc + arow + kc * 32);
      }
#pragma unroll
      for (int rg = 0; rg < 4; ++rg) {
        int n = n0 + quad * 4 + rg;
        hold2[rg] = h[(size_t)n * HID + d];
        degf2[rg] = (float)deg[n];
      }
    }

    f32x4 acc[6] = {};
#pragma unroll
    for (int kc = 0; kc < 4; ++kc)
#pragma unroll
      for (int g = 0; g < 3; ++g) {
        acc[g]     = __builtin_amdgcn_mfma_f32_16x16x32_bf16(af[kc].b, bw[g][kc].b, acc[g], 0, 0, 0);
        acc[3 + g] = __builtin_amdgcn_mfma_f32_16x16x32_bf16(hf[kc].b, bh[g][kc].b, acc[3 + g], 0, 0, 0);
      }

    int n0 = s << 4;
#pragma unroll
    for (int rg = 0; rg < 4; ++rg) {
      float ir = acc[0][rg] + degf[rg] * vr + bir;
      float iz = acc[1][rg] + degf[rg] * vz + biz;
      float in_ = acc[2][rg] + degf[rg] * vn + bin_;
      float hr = acc[3][rg] + bhr;
      float hz = acc[4][rg] + bhz;
      float hn = acc[5][rg] + bhn;
      float r = 1.f / (1.f + __expf(-(ir + hr)));
      float z = 1.f / (1.f + __expf(-(iz + hz)));
      float x2 = in_ + r * hn;
      float e2 = __expf(2.f * x2);
      float nv = 1.f - 2.f / (e2 + 1.f);   // tanh
      float hv = (1.f - z) * nv + z * hold[rg];
      size_t o = (size_t)(n0 + quad * 4 + rg) * HID + d;
      h[o] = hv;
      hbn[o] = f2bf(hv);
    }

    if (!more) break;
    s = ns;
#pragma unroll
    for (int kc = 0; kc < 4; ++kc) { af[kc] = af2[kc]; hf[kc] = hf2[kc]; }
#pragma unroll
    for (int rg = 0; rg < 4; ++rg) { hold[rg] = hold2[rg]; degf[rg] = degf2[rg]; }
  }
}

// ---- per-graph counts from SORTED gid: binary search, no atomics
__global__ __launch_bounds__(64) void k_bounds(const int* __restrict__ gid,
                                               int* __restrict__ cnt, int N, int G) {
  int g = threadIdx.x;
  if (g >= G) return;
  int lo = 0, hi = N;
  while (lo < hi) { int mid = (lo + hi) >> 1; if (gid[mid] < g) lo = mid + 1; else hi = mid; }
  int lb0 = lo;
  lo = 0; hi = N;
  int g1 = g + 1;
  while (lo < hi) { int mid = (lo + hi) >> 1; if (gid[mid] < g1) lo = mid + 1; else hi = mid; }
  cnt[g] = lo - lb0;
}

// ---- pooling: graph_ids sorted -> run-length accumulate, few atomics
#define POOL_CHUNK 96
__global__ __launch_bounds__(128) void k_pool(const float* __restrict__ h,
                                              const int* __restrict__ gid,
                                              float* __restrict__ hg, int N) {
  int d = threadIdx.x;
  int start = blockIdx.x * POOL_CHUNK;
  if (start >= N) return;
  int end = min(start + POOL_CHUNK, N);
  float acc = 0.f;
  int g = gid[start];
  for (int n = start; n < end; ++n) {
    int gn = gid[n];
    if (gn != g) { unsafeAtomicAdd(&hg[g * HID + d], acc); acc = 0.f; g = gn; }
    acc += fmaxf(h[(size_t)n * HID + d], 0.f);   // relu
  }
  unsafeAtomicAdd(&hg[g * HID + d], acc);
}

__global__ __launch_bounds__(640) void k_cls(const float* __restrict__ hg,
                                             const int* __restrict__ cnt,
                                             const float* __restrict__ Wc,
                                             const float* __restrict__ bc,
                                             float* __restrict__ out, int G) {
  int t = threadIdx.x;
  if (t >= G * 10) return;
  int g = t / 10, c = t % 10;
  float inv = 1.f / fmaxf((float)cnt[g], 1.f);
  float acc = 0.f;
  for (int d = 0; d < HID; ++d) acc = fmaf(hg[g * HID + d], Wc[c * HID + d], acc);
  out[t] = acc * inv + bc[c];
}

extern "C" void kernel_launch(void* const* d_in, const int* in_sizes, int n_in,
                              void* d_out, int out_size, void* d_ws, size_t ws_size,
                              hipStream_t stream) {
  const int N = in_sizes[0];
  const int E = in_sizes[9];
  const float* m    = (const float*)d_in[0];
  const float* W_e  = (const float*)d_in[1];
  const float* b_e  = (const float*)d_in[2];
  const float* W_ih = (const float*)d_in[3];
  const float* b_ih = (const float*)d_in[4];
  const float* W_hh = (const float*)d_in[5];
  const float* b_hh = (const float*)d_in[6];
  const float* W_cls = (const float*)d_in[7];
  const float* b_cls = (const float*)d_in[8];
  const int* src = (const int*)d_in[9];
  const int* dst = (const int*)d_in[10];
  const int* gid = (const int*)d_in[11];
  const int G = out_size / 10;
  float* out = (float*)d_out;

  size_t off = 0;
  auto alloc = [&](size_t b) {
    char* p = (char*)d_ws + off;
    off += (b + 255) & ~(size_t)255;
    return (void*)p;
  };
  float*  h      = (float*) alloc((size_t)N * HID * 4);
  ushort* hb0    = (ushort*)alloc((size_t)N * HID * 2);
  ushort* hb1    = (ushort*)alloc((size_t)N * HID * 2);
  ushort* hs16   = (ushort*)alloc((size_t)N * HID * 2);
  int*    deg    = (int*)   alloc((size_t)N * 4);
  int*    rowptr = (int*)   alloc((size_t)(N + 1) * 4);
  int*    cursor = (int*)   alloc((size_t)N * 4);
  int*    csrc   = (int*)   alloc((size_t)E * 4);
  int*    bsum   = (int*)   alloc(64 * 4);
  int*    boff   = (int*)   alloc(64 * 4);
  ushort* Wcomb  = (ushort*)alloc((size_t)G3 * HID * 2);
  ushort* Whh16  = (ushort*)alloc((size_t)G3 * HID * 2);
  float*  bvec   = (float*) alloc((size_t)G3 * 4);
  float*  hg     = (float*) alloc((size_t)G * HID * 4);
  int*    cnt    = (int*)   alloc((size_t)G * 4);
  if (off > ws_size) return;   // workspace too small -> visible failure

  k_weights<<<2 * G3, HID, 0, stream>>>(W_e, b_e, W_ih, W_hh, Wcomb, Whh16, bvec);
  hipMemsetAsync(deg, 0, (size_t)N * 4, stream);
  hipMemsetAsync(cursor, 0, (size_t)N * 4, stream);
  k_deg<<<(E + 255) / 256, 256, 0, stream>>>(dst, deg, E);
  int B = (N + SCAN_TILE - 1) / SCAN_TILE;
  if (B <= 64) {
    k_scan1<<<B, 256, 0, stream>>>(deg, bsum, N);
    k_scan2<<<1, 64, 0, stream>>>(bsum, boff, rowptr, B, N);
    k_scan3<<<B, 256, 0, stream>>>(deg, boff, rowptr, N);
  } else {
    k_scan<<<1, 1024, 0, stream>>>(deg, rowptr, N);
  }
  k_fill<<<(E + 255) / 256, 256, 0, stream>>>(src, dst, rowptr, cursor, csrc, E);
  k_init<<<(N * HID + 255) / 256, 256, 0, stream>>>(m, h, hb0, N);

  ushort* hbc = hb0;
  ushort* hbn = hb1;
  for (int s = 0; s < TSTEPS; ++s) {
    k_gather<<<(N + 3) / 4, 256, 0, stream>>>(rowptr, csrc, hbc, hs16, N);
    int nstrip = N >> 4;
    int blocks = nstrip < 1024 ? nstrip : 1024;
    k_gru<<<blocks, 512, 0, stream>>>(hs16, h, hbc, hbn, Wcomb, Whh16, bvec, b_ih, b_hh, deg, N);
    ushort* t = hbc; hbc = hbn; hbn = t;
  }

  hipMemsetAsync(hg, 0, (size_t)G * HID * 4, stream);
  k_bounds<<<1, 64, 0, stream>>>(gid, cnt, N, G);
  k_pool<<<(N + POOL_CHUNK - 1) / POOL_CHUNK, HID, 0, stream>>>(h, gid, hg, N);
  k_cls<<<1, 640, 0, stream>>>(hg, cnt, W_cls, b_cls, out, G);
}

// Round 6
// 1091.201 us; speedup vs baseline: 28.6933x; 1.0425x over previous
//
#include <hip/hip_runtime.h>

#define HID 128
#define G3  384   // 3*HID
#define TSTEPS 5
#define SCAN_TILE 2048   // 256 thr * 8 elems

typedef unsigned int  uint;
typedef unsigned short ushort;

typedef float  f32x4  __attribute__((ext_vector_type(4)));
typedef __bf16 bf16x8 __attribute__((ext_vector_type(8)));

union B8u { uint4 u; bf16x8 b; ushort s[8]; };

static __device__ inline ushort f2bf(float f) {
  uint u = __float_as_uint(f);
  uint r = u + 0x7fffu + ((u >> 16) & 1u);   // RTN-even
  return (ushort)(r >> 16);
}
static __device__ inline float bf2f(ushort s) {
  return __uint_as_float(((uint)s) << 16);
}

// ---- once per call: W_comb = W_ih @ W_e (bf16), bvec = W_ih @ b_e, W_hh -> bf16
__global__ __launch_bounds__(128) void k_weights(
    const float* __restrict__ W_e, const float* __restrict__ b_e,
    const float* __restrict__ W_ih, const float* __restrict__ W_hh,
    ushort* __restrict__ Wcomb, ushort* __restrict__ Whh16, float* __restrict__ bvec)
{
  int j = blockIdx.x, t = threadIdx.x;
  if (j < G3) {
    __shared__ float row[HID];
    row[t] = W_ih[j * HID + t];
    __syncthreads();
    float acc = 0.f;
    for (int k = 0; k < HID; ++k) acc = fmaf(row[k], W_e[k * HID + t], acc);
    Wcomb[j * HID + t] = f2bf(acc);
    if (t == 0) {
      float b = 0.f;
      for (int k = 0; k < HID; ++k) b += row[k] * b_e[k];
      bvec[j] = b;
    }
  } else {
    int j2 = j - G3;
    Whh16[j2 * HID + t] = f2bf(W_hh[j2 * HID + t]);
  }
}

__global__ void k_deg(const int* __restrict__ dst, int* __restrict__ deg, int E) {
  int e = blockIdx.x * 256 + threadIdx.x;
  if (e < E) atomicAdd(&deg[dst[e]], 1);
}

// ---- 3-phase hierarchical scan of deg -> rowptr (exclusive), rowptr[N]=total
__global__ __launch_bounds__(256) void k_scan1(const int* __restrict__ deg,
                                               int* __restrict__ bsum, int N) {
  int base = blockIdx.x * SCAN_TILE + threadIdx.x * 8;
  int s = 0;
#pragma unroll
  for (int i = 0; i < 8; ++i) { int idx = base + i; if (idx < N) s += deg[idx]; }
  int lane = threadIdx.x & 63;
#pragma unroll
  for (int off = 32; off > 0; off >>= 1) s += __shfl_down(s, off, 64);
  __shared__ int ws[4];
  if (lane == 0) ws[threadIdx.x >> 6] = s;
  __syncthreads();
  if (threadIdx.x == 0) bsum[blockIdx.x] = ws[0] + ws[1] + ws[2] + ws[3];
}

__global__ __launch_bounds__(64) void k_scan2(const int* __restrict__ bsum,
                                              int* __restrict__ boff,
                                              int* __restrict__ rowptr, int B, int N) {
  int t = threadIdx.x;
  int orig = (t < B) ? bsum[t] : 0;
  int v = orig;
#pragma unroll
  for (int off = 1; off < 64; off <<= 1) {
    int u = __shfl_up(v, off, 64);
    if (t >= off) v += u;
  }
  if (t < B) boff[t] = v - orig;
  if (t == B - 1) rowptr[N] = v;   // total
}

__global__ __launch_bounds__(256) void k_scan3(const int* __restrict__ deg,
                                               const int* __restrict__ boff,
                                               int* __restrict__ rowptr, int N) {
  int base = blockIdx.x * SCAN_TILE + threadIdx.x * 8;
  int x[8]; int s = 0;
#pragma unroll
  for (int i = 0; i < 8; ++i) { int idx = base + i; x[i] = (idx < N) ? deg[idx] : 0; s += x[i]; }
  int lane = threadIdx.x & 63, wv = threadIdx.x >> 6;
  int incl = s;
#pragma unroll
  for (int off = 1; off < 64; off <<= 1) {
    int u = __shfl_up(incl, off, 64);
    if (lane >= off) incl += u;
  }
  __shared__ int wsum[4];
  if (lane == 63) wsum[wv] = incl;
  __syncthreads();
  int wbase = 0;
  for (int i = 0; i < wv; ++i) wbase += wsum[i];
  int run = boff[blockIdx.x] + wbase + (incl - s);
#pragma unroll
  for (int i = 0; i < 8; ++i) { int idx = base + i; if (idx < N) rowptr[idx] = run; run += x[i]; }
}

// fallback single-block scan (only if N > 64*SCAN_TILE)
__global__ __launch_bounds__(1024) void k_scan(const int* __restrict__ deg,
                                               int* __restrict__ rowptr, int N) {
  __shared__ int part[1024];
  int t = threadIdx.x;
  int chunk = (N + 1023) / 1024;
  int b = t * chunk, e = min(b + chunk, N);
  if (b > N) { b = N; }
  int s = 0;
  for (int i = b; i < e; ++i) s += deg[i];
  part[t] = s;
  __syncthreads();
  for (int off = 1; off < 1024; off <<= 1) {
    int x = (t >= off) ? part[t - off] : 0;
    __syncthreads();
    part[t] += x;
    __syncthreads();
  }
  int run = part[t] - s;
  for (int i = b; i < e; ++i) { rowptr[i] = run; run += deg[i]; }
  if (t == 1023) rowptr[N] = part[1023];
}

__global__ void k_fill(const int* __restrict__ src, const int* __restrict__ dst,
                       const int* __restrict__ rowptr, int* __restrict__ cursor,
                       int* __restrict__ csrc, int E) {
  int e = blockIdx.x * 256 + threadIdx.x;
  if (e >= E) return;
  int d = dst[e];
  int p = atomicAdd(&cursor[d], 1);
  csrc[rowptr[d] + p] = src[e];
}

__global__ void k_init(const float* __restrict__ m, float* __restrict__ h,
                       ushort* __restrict__ hb, int N) {
  int idx = blockIdx.x * 256 + threadIdx.x;
  if (idx >= N * HID) return;
  int d = idx & (HID - 1);
  float v = (d == 0) ? m[idx >> 7] : 0.f;
  h[idx] = v;
  hb[idx] = f2bf(v);
}

// ---- gather: hs16[v] = bf16( sum_{u in N_in(v)} h[u] ); one wave per node.
// Wave split into 4 x 16-lane groups: group g handles edge slot g with
// dwordx4 row loads (lane i owns dims [8i,8i+8)). One unrolled iteration
// puts 16 edges (4 KB) in flight. Cross-group reduce via shfl_xor(16,32).
__global__ __launch_bounds__(256) void k_gather(
    const int* __restrict__ rowptr, const int* __restrict__ csrc,
    const ushort* __restrict__ hb, ushort* __restrict__ hs16, int N)
{
  int v = blockIdx.x * 4 + (threadIdx.x >> 6);
  if (v >= N) return;
  int lane = threadIdx.x & 63;
  int g = lane >> 4;        // edge slot 0..3
  int i = lane & 15;        // 16B chunk of row
  int beg = rowptr[v], end = rowptr[v + 1];
  float acc[8] = {0.f, 0.f, 0.f, 0.f, 0.f, 0.f, 0.f, 0.f};
  int e = beg;
  for (; e + 16 <= end; e += 16) {      // 16 edges in flight
    int s0 = csrc[e + g];
    int s1 = csrc[e + 4 + g];
    int s2 = csrc[e + 8 + g];
    int s3 = csrc[e + 12 + g];
    B8u w0; w0.u = *(const uint4*)(hb + (size_t)s0 * HID + i * 8);
    B8u w1; w1.u = *(const uint4*)(hb + (size_t)s1 * HID + i * 8);
    B8u w2; w2.u = *(const uint4*)(hb + (size_t)s2 * HID + i * 8);
    B8u w3; w3.u = *(const uint4*)(hb + (size_t)s3 * HID + i * 8);
#pragma unroll
    for (int j = 0; j < 8; ++j)
      acc[j] += (bf2f(w0.s[j]) + bf2f(w1.s[j])) + (bf2f(w2.s[j]) + bf2f(w3.s[j]));
  }
  for (; e < end; e += 4) {             // predicated 4-edge tail
    int ee = e + g;
    if (ee < end) {
      int s0 = csrc[ee];
      B8u w; w.u = *(const uint4*)(hb + (size_t)s0 * HID + i * 8);
#pragma unroll
      for (int j = 0; j < 8; ++j) acc[j] += bf2f(w.s[j]);
    }
  }
#pragma unroll
  for (int j = 0; j < 8; ++j) {
    acc[j] += __shfl_xor(acc[j], 16, 64);
    acc[j] += __shfl_xor(acc[j], 32, 64);
  }
  if (g == 0) {
    uint4 ov;
    ov.x = ((uint)f2bf(acc[1]) << 16) | (uint)f2bf(acc[0]);
    ov.y = ((uint)f2bf(acc[3]) << 16) | (uint)f2bf(acc[2]);
    ov.z = ((uint)f2bf(acc[5]) << 16) | (uint)f2bf(acc[4]);
    ov.w = ((uint)f2bf(acc[7]) << 16) | (uint)f2bf(acc[6]);
    *(uint4*)(hs16 + (size_t)v * HID + i * 8) = ov;
  }
}

// ---- fused GEMM + GRU. Weights live in VGPRs for the whole kernel; block
// grid-strides over 16-node strips with manual double-buffered A/epilogue
// loads. hb ping-pongs across steps (no barriers); h fp32 in place.
__global__ __launch_bounds__(512, 2) void k_gru(
    const ushort* __restrict__ hs16, float* __restrict__ h,
    const ushort* __restrict__ hbc, ushort* __restrict__ hbn,
    const ushort* __restrict__ Wcomb, const ushort* __restrict__ Whh16,
    const float* __restrict__ bvec, const float* __restrict__ b_ih,
    const float* __restrict__ b_hh, const int* __restrict__ deg, int N)
{
  const int w = threadIdx.x >> 6;
  const int lane = threadIdx.x & 63;
  const int quad = lane >> 4, l16 = lane & 15;
  const int d0 = w * 16;
  const int d = d0 + l16;

  B8u bw[3][4], bh[3][4];
#pragma unroll
  for (int g = 0; g < 3; ++g)
#pragma unroll
    for (int kc = 0; kc < 4; ++kc) {
      int j = (d0 + g * 128 + l16) * HID + kc * 32 + quad * 8;
      bw[g][kc].u = *(const uint4*)(Wcomb + j);
      bh[g][kc].u = *(const uint4*)(Whh16 + j);
    }
  const float bir = b_ih[d], biz = b_ih[d + 128], bin_ = b_ih[d + 256];
  const float bhr = b_hh[d], bhz = b_hh[d + 128], bhn = b_hh[d + 256];
  const float vr = bvec[d], vz = bvec[d + 128], vn = bvec[d + 256];

  const int nstrip = N >> 4;
  int s = blockIdx.x;
  if (s >= nstrip) return;

  B8u af[4], hf[4]; float hold[4], degf[4];
  {
    int n0 = s << 4;
    size_t arow = (size_t)(n0 + l16) * HID + quad * 8;
#pragma unroll
    for (int kc = 0; kc < 4; ++kc) {
      af[kc].u = *(const uint4*)(hs16 + arow + kc * 32);
      hf[kc].u = *(const uint4*)(hbc + arow + kc * 32);
    }
#pragma unroll
    for (int rg = 0; rg < 4; ++rg) {
      int n = n0 + quad * 4 + rg;
      hold[rg] = h[(size_t)n * HID + d];
      degf[rg] = (float)deg[n];
    }
  }

  while (true) {
    int ns = s + (int)gridDim.x;
    bool more = ns < nstrip;
    B8u af2[4], hf2[4]; float hold2[4], degf2[4];
    if (more) {
      int n0 = ns << 4;
      size_t arow = (size_t)(n0 + l16) * HID + quad * 8;
#pragma unroll
      for (int kc = 0; kc < 4; ++kc) {
        af2[kc].u = *(const uint4*)(hs16 + arow + kc * 32);
        hf2[kc].u = *(const uint4*)(hbc + arow + kc * 32);
      }
#pragma unroll
      for (int rg = 0; rg < 4; ++rg) {
        int n = n0 + quad * 4 + rg;
        hold2[rg] = h[(size_t)n * HID + d];
        degf2[rg] = (float)deg[n];
      }
    }

    f32x4 acc[6] = {};
#pragma unroll
    for (int kc = 0; kc < 4; ++kc)
#pragma unroll
      for (int g = 0; g < 3; ++g) {
        acc[g]     = __builtin_amdgcn_mfma_f32_16x16x32_bf16(af[kc].b, bw[g][kc].b, acc[g], 0, 0, 0);
        acc[3 + g] = __builtin_amdgcn_mfma_f32_16x16x32_bf16(hf[kc].b, bh[g][kc].b, acc[3 + g], 0, 0, 0);
      }

    int n0 = s << 4;
#pragma unroll
    for (int rg = 0; rg < 4; ++rg) {
      float ir = acc[0][rg] + degf[rg] * vr + bir;
      float iz = acc[1][rg] + degf[rg] * vz + biz;
      float in_ = acc[2][rg] + degf[rg] * vn + bin_;
      float hr = acc[3][rg] + bhr;
      float hz = acc[4][rg] + bhz;
      float hn = acc[5][rg] + bhn;
      float r = 1.f / (1.f + __expf(-(ir + hr)));
      float z = 1.f / (1.f + __expf(-(iz + hz)));
      float x2 = in_ + r * hn;
      float e2 = __expf(2.f * x2);
      float nv = 1.f - 2.f / (e2 + 1.f);   // tanh
      float hv = (1.f - z) * nv + z * hold[rg];
      size_t o = (size_t)(n0 + quad * 4 + rg) * HID + d;
      h[o] = hv;
      hbn[o] = f2bf(hv);
    }

    if (!more) break;
    s = ns;
#pragma unroll
    for (int kc = 0; kc < 4; ++kc) { af[kc] = af2[kc]; hf[kc] = hf2[kc]; }
#pragma unroll
    for (int rg = 0; rg < 4; ++rg) { hold[rg] = hold2[rg]; degf[rg] = degf2[rg]; }
  }
}

// ---- per-graph counts from SORTED gid: binary search, no atomics
__global__ __launch_bounds__(64) void k_bounds(const int* __restrict__ gid,
                                               int* __restrict__ cnt, int N, int G) {
  int g = threadIdx.x;
  if (g >= G) return;
  int lo = 0, hi = N;
  while (lo < hi) { int mid = (lo + hi) >> 1; if (gid[mid] < g) lo = mid + 1; else hi = mid; }
  int lb0 = lo;
  lo = 0; hi = N;
  int g1 = g + 1;
  while (lo < hi) { int mid = (lo + hi) >> 1; if (gid[mid] < g1) lo = mid + 1; else hi = mid; }
  cnt[g] = lo - lb0;
}

// ---- pooling: graph_ids sorted -> run-length accumulate, few atomics
#define POOL_CHUNK 96
__global__ __launch_bounds__(128) void k_pool(const float* __restrict__ h,
                                              const int* __restrict__ gid,
                                              float* __restrict__ hg, int N) {
  int d = threadIdx.x;
  int start = blockIdx.x * POOL_CHUNK;
  if (start >= N) return;
  int end = min(start + POOL_CHUNK, N);
  float acc = 0.f;
  int g = gid[start];
  for (int n = start; n < end; ++n) {
    int gn = gid[n];
    if (gn != g) { unsafeAtomicAdd(&hg[g * HID + d], acc); acc = 0.f; g = gn; }
    acc += fmaxf(h[(size_t)n * HID + d], 0.f);   // relu
  }
  unsafeAtomicAdd(&hg[g * HID + d], acc);
}

__global__ __launch_bounds__(640) void k_cls(const float* __restrict__ hg,
                                             const int* __restrict__ cnt,
                                             const float* __restrict__ Wc,
                                             const float* __restrict__ bc,
                                             float* __restrict__ out, int G) {
  int t = threadIdx.x;
  if (t >= G * 10) return;
  int g = t / 10, c = t % 10;
  float inv = 1.f / fmaxf((float)cnt[g], 1.f);
  float acc = 0.f;
  for (int d = 0; d < HID; ++d) acc = fmaf(hg[g * HID + d], Wc[c * HID + d], acc);
  out[t] = acc * inv + bc[c];
}

extern "C" void kernel_launch(void* const* d_in, const int* in_sizes, int n_in,
                              void* d_out, int out_size, void* d_ws, size_t ws_size,
                              hipStream_t stream) {
  const int N = in_sizes[0];
  const int E = in_sizes[9];
  const float* m    = (const float*)d_in[0];
  const float* W_e  = (const float*)d_in[1];
  const float* b_e  = (const float*)d_in[2];
  const float* W_ih = (const float*)d_in[3];
  const float* b_ih = (const float*)d_in[4];
  const float* W_hh = (const float*)d_in[5];
  const float* b_hh = (const float*)d_in[6];
  const float* W_cls = (const float*)d_in[7];
  const float* b_cls = (const float*)d_in[8];
  const int* src = (const int*)d_in[9];
  const int* dst = (const int*)d_in[10];
  const int* gid = (const int*)d_in[11];
  const int G = out_size / 10;
  float* out = (float*)d_out;

  size_t off = 0;
  auto alloc = [&](size_t b) {
    char* p = (char*)d_ws + off;
    off += (b + 255) & ~(size_t)255;
    return (void*)p;
  };
  float*  h      = (float*) alloc((size_t)N * HID * 4);
  ushort* hb0    = (ushort*)alloc((size_t)N * HID * 2);
  ushort* hb1    = (ushort*)alloc((size_t)N * HID * 2);
  ushort* hs16   = (ushort*)alloc((size_t)N * HID * 2);
  int*    deg    = (int*)   alloc((size_t)N * 4);
  int*    rowptr = (int*)   alloc((size_t)(N + 1) * 4);
  int*    cursor = (int*)   alloc((size_t)N * 4);
  int*    csrc   = (int*)   alloc((size_t)E * 4);
  int*    bsum   = (int*)   alloc(64 * 4);
  int*    boff   = (int*)   alloc(64 * 4);
  ushort* Wcomb  = (ushort*)alloc((size_t)G3 * HID * 2);
  ushort* Whh16  = (ushort*)alloc((size_t)G3 * HID * 2);
  float*  bvec   = (float*) alloc((size_t)G3 * 4);
  float*  hg     = (float*) alloc((size_t)G * HID * 4);
  int*    cnt    = (int*)   alloc((size_t)G * 4);
  if (off > ws_size) return;   // workspace too small -> visible failure

  k_weights<<<2 * G3, HID, 0, stream>>>(W_e, b_e, W_ih, W_hh, Wcomb, Whh16, bvec);
  hipMemsetAsync(deg, 0, (size_t)N * 4, stream);
  hipMemsetAsync(cursor, 0, (size_t)N * 4, stream);
  k_deg<<<(E + 255) / 256, 256, 0, stream>>>(dst, deg, E);
  int B = (N + SCAN_TILE - 1) / SCAN_TILE;
  if (B <= 64) {
    k_scan1<<<B, 256, 0, stream>>>(deg, bsum, N);
    k_scan2<<<1, 64, 0, stream>>>(bsum, boff, rowptr, B, N);
    k_scan3<<<B, 256, 0, stream>>>(deg, boff, rowptr, N);
  } else {
    k_scan<<<1, 1024, 0, stream>>>(deg, rowptr, N);
  }
  k_fill<<<(E + 255) / 256, 256, 0, stream>>>(src, dst, rowptr, cursor, csrc, E);
  k_init<<<(N * HID + 255) / 256, 256, 0, stream>>>(m, h, hb0, N);

  ushort* hbc = hb0;
  ushort* hbn = hb1;
  for (int s = 0; s < TSTEPS; ++s) {
    k_gather<<<(N + 3) / 4, 256, 0, stream>>>(rowptr, csrc, hbc, hs16, N);
    int nstrip = N >> 4;
    int blocks = nstrip < 1024 ? nstrip : 1024;
    k_gru<<<blocks, 512, 0, stream>>>(hs16, h, hbc, hbn, Wcomb, Whh16, bvec, b_ih, b_hh, deg, N);
    ushort* t = hbc; hbc = hbn; hbn = t;
  }

  hipMemsetAsync(hg, 0, (size_t)G * HID * 4, stream);
  k_bounds<<<1, 64, 0, stream>>>(gid, cnt, N, G);
  k_pool<<<(N + POOL_CHUNK - 1) / POOL_CHUNK, HID, 0, stream>>>(h, gid, hg, N);
  k_cls<<<1, 640, 0, stream>>>(hg, cnt, W_cls, b_cls, out, G);
}

// Round 7
// 1059.630 us; speedup vs baseline: 29.5482x; 1.0298x over previous
//
#include <hip/hip_runtime.h>

#define HID 128
#define G3  384   // 3*HID
#define TSTEPS 5
#define SCAN_TILE 2048   // 256 thr * 8 elems

typedef unsigned int  uint;
typedef unsigned short ushort;

typedef float  f32x4  __attribute__((ext_vector_type(4)));
typedef __bf16 bf16x8 __attribute__((ext_vector_type(8)));

union B8u { uint4 u; bf16x8 b; ushort s[8]; };

static __device__ inline ushort f2bf(float f) {
  uint u = __float_as_uint(f);
  uint r = u + 0x7fffu + ((u >> 16) & 1u);   // RTN-even
  return (ushort)(r >> 16);
}
static __device__ inline float bf2f(ushort s) {
  return __uint_as_float(((uint)s) << 16);
}

// ---- once per call: W_comb = W_ih @ W_e (bf16), bvec = W_ih @ b_e, W_hh -> bf16
__global__ __launch_bounds__(128) void k_weights(
    const float* __restrict__ W_e, const float* __restrict__ b_e,
    const float* __restrict__ W_ih, const float* __restrict__ W_hh,
    ushort* __restrict__ Wcomb, ushort* __restrict__ Whh16, float* __restrict__ bvec)
{
  int j = blockIdx.x, t = threadIdx.x;
  if (j < G3) {
    __shared__ float row[HID];
    row[t] = W_ih[j * HID + t];
    __syncthreads();
    float acc = 0.f;
    for (int k = 0; k < HID; ++k) acc = fmaf(row[k], W_e[k * HID + t], acc);
    Wcomb[j * HID + t] = f2bf(acc);
    if (t == 0) {
      float b = 0.f;
      for (int k = 0; k < HID; ++k) b += row[k] * b_e[k];
      bvec[j] = b;
    }
  } else {
    int j2 = j - G3;
    Whh16[j2 * HID + t] = f2bf(W_hh[j2 * HID + t]);
  }
}

__global__ void k_deg(const int* __restrict__ dst, int* __restrict__ deg, int E) {
  int e = blockIdx.x * 256 + threadIdx.x;
  if (e < E) atomicAdd(&deg[dst[e]], 1);
}

// ---- 3-phase hierarchical scan of deg -> rowptr (exclusive), rowptr[N]=total
__global__ __launch_bounds__(256) void k_scan1(const int* __restrict__ deg,
                                               int* __restrict__ bsum, int N) {
  int base = blockIdx.x * SCAN_TILE + threadIdx.x * 8;
  int s = 0;
#pragma unroll
  for (int i = 0; i < 8; ++i) { int idx = base + i; if (idx < N) s += deg[idx]; }
  int lane = threadIdx.x & 63;
#pragma unroll
  for (int off = 32; off > 0; off >>= 1) s += __shfl_down(s, off, 64);
  __shared__ int ws[4];
  if (lane == 0) ws[threadIdx.x >> 6] = s;
  __syncthreads();
  if (threadIdx.x == 0) bsum[blockIdx.x] = ws[0] + ws[1] + ws[2] + ws[3];
}

__global__ __launch_bounds__(64) void k_scan2(const int* __restrict__ bsum,
                                              int* __restrict__ boff,
                                              int* __restrict__ rowptr, int B, int N) {
  int t = threadIdx.x;
  int orig = (t < B) ? bsum[t] : 0;
  int v = orig;
#pragma unroll
  for (int off = 1; off < 64; off <<= 1) {
    int u = __shfl_up(v, off, 64);
    if (t >= off) v += u;
  }
  if (t < B) boff[t] = v - orig;
  if (t == B - 1) rowptr[N] = v;   // total
}

__global__ __launch_bounds__(256) void k_scan3(const int* __restrict__ deg,
                                               const int* __restrict__ boff,
                                               int* __restrict__ rowptr, int N) {
  int base = blockIdx.x * SCAN_TILE + threadIdx.x * 8;
  int x[8]; int s = 0;
#pragma unroll
  for (int i = 0; i < 8; ++i) { int idx = base + i; x[i] = (idx < N) ? deg[idx] : 0; s += x[i]; }
  int lane = threadIdx.x & 63, wv = threadIdx.x >> 6;
  int incl = s;
#pragma unroll
  for (int off = 1; off < 64; off <<= 1) {
    int u = __shfl_up(incl, off, 64);
    if (lane >= off) incl += u;
  }
  __shared__ int wsum[4];
  if (lane == 63) wsum[wv] = incl;
  __syncthreads();
  int wbase = 0;
  for (int i = 0; i < wv; ++i) wbase += wsum[i];
  int run = boff[blockIdx.x] + wbase + (incl - s);
#pragma unroll
  for (int i = 0; i < 8; ++i) { int idx = base + i; if (idx < N) rowptr[idx] = run; run += x[i]; }
}

// fallback single-block scan (only if N > 64*SCAN_TILE)
__global__ __launch_bounds__(1024) void k_scan(const int* __restrict__ deg,
                                               int* __restrict__ rowptr, int N) {
  __shared__ int part[1024];
  int t = threadIdx.x;
  int chunk = (N + 1023) / 1024;
  int b = t * chunk, e = min(b + chunk, N);
  if (b > N) { b = N; }
  int s = 0;
  for (int i = b; i < e; ++i) s += deg[i];
  part[t] = s;
  __syncthreads();
  for (int off = 1; off < 1024; off <<= 1) {
    int x = (t >= off) ? part[t - off] : 0;
    __syncthreads();
    part[t] += x;
    __syncthreads();
  }
  int run = part[t] - s;
  for (int i = b; i < e; ++i) { rowptr[i] = run; run += deg[i]; }
  if (t == 1023) rowptr[N] = part[1023];
}

__global__ void k_fill(const int* __restrict__ src, const int* __restrict__ dst,
                       const int* __restrict__ rowptr, int* __restrict__ cursor,
                       int* __restrict__ csrc, int E) {
  int e = blockIdx.x * 256 + threadIdx.x;
  if (e >= E) return;
  int d = dst[e];
  int p = atomicAdd(&cursor[d], 1);
  csrc[rowptr[d] + p] = src[e];
}

__global__ void k_init(const float* __restrict__ m, ushort* __restrict__ hb, int N) {
  int idx = blockIdx.x * 256 + threadIdx.x;
  if (idx >= N * HID) return;
  int d = idx & (HID - 1);
  float v = (d == 0) ? m[idx >> 7] : 0.f;
  hb[idx] = f2bf(v);
}

// ---- gather: hs16[v] = bf16( sum_{u in N_in(v)} h[u] ); one wave per node.
// Wave split into 4 x 16-lane groups: group g handles edge slot g with
// dwordx4 row loads (lane i owns dims [8i,8i+8)). One unrolled iteration
// puts 16 edges (4 KB) in flight. Cross-group reduce via shfl_xor(16,32).
__global__ __launch_bounds__(256) void k_gather(
    const int* __restrict__ rowptr, const int* __restrict__ csrc,
    const ushort* __restrict__ hb, ushort* __restrict__ hs16, int N)
{
  int v = blockIdx.x * 4 + (threadIdx.x >> 6);
  if (v >= N) return;
  int lane = threadIdx.x & 63;
  int g = lane >> 4;        // edge slot 0..3
  int i = lane & 15;        // 16B chunk of row
  int beg = rowptr[v], end = rowptr[v + 1];
  float acc[8] = {0.f, 0.f, 0.f, 0.f, 0.f, 0.f, 0.f, 0.f};
  int e = beg;
  for (; e + 16 <= end; e += 16) {      // 16 edges in flight
    int s0 = csrc[e + g];
    int s1 = csrc[e + 4 + g];
    int s2 = csrc[e + 8 + g];
    int s3 = csrc[e + 12 + g];
    B8u w0; w0.u = *(const uint4*)(hb + (size_t)s0 * HID + i * 8);
    B8u w1; w1.u = *(const uint4*)(hb + (size_t)s1 * HID + i * 8);
    B8u w2; w2.u = *(const uint4*)(hb + (size_t)s2 * HID + i * 8);
    B8u w3; w3.u = *(const uint4*)(hb + (size_t)s3 * HID + i * 8);
#pragma unroll
    for (int j = 0; j < 8; ++j)
      acc[j] += (bf2f(w0.s[j]) + bf2f(w1.s[j])) + (bf2f(w2.s[j]) + bf2f(w3.s[j]));
  }
  for (; e < end; e += 4) {             // predicated 4-edge tail
    int ee = e + g;
    if (ee < end) {
      int s0 = csrc[ee];
      B8u w; w.u = *(const uint4*)(hb + (size_t)s0 * HID + i * 8);
#pragma unroll
      for (int j = 0; j < 8; ++j) acc[j] += bf2f(w.s[j]);
    }
  }
#pragma unroll
  for (int j = 0; j < 8; ++j) {
    acc[j] += __shfl_xor(acc[j], 16, 64);
    acc[j] += __shfl_xor(acc[j], 32, 64);
  }
  if (g == 0) {
    uint4 ov;
    ov.x = ((uint)f2bf(acc[1]) << 16) | (uint)f2bf(acc[0]);
    ov.y = ((uint)f2bf(acc[3]) << 16) | (uint)f2bf(acc[2]);
    ov.z = ((uint)f2bf(acc[5]) << 16) | (uint)f2bf(acc[4]);
    ov.w = ((uint)f2bf(acc[7]) << 16) | (uint)f2bf(acc[6]);
    *(uint4*)(hs16 + (size_t)v * HID + i * 8) = ov;
  }
}

// ---- fused GEMM + GRU. Weights live in VGPRs for the whole kernel; block
// grid-strides over 16-node strips with manual double-buffered A/epilogue
// loads. State is bf16-only: hold re-read from hbc (L1-hot — the strip's
// rows were just fetched as MFMA A-fragments); only hbn written.
__global__ __launch_bounds__(512, 2) void k_gru(
    const ushort* __restrict__ hs16,
    const ushort* __restrict__ hbc, ushort* __restrict__ hbn,
    const ushort* __restrict__ Wcomb, const ushort* __restrict__ Whh16,
    const float* __restrict__ bvec, const float* __restrict__ b_ih,
    const float* __restrict__ b_hh, const int* __restrict__ deg, int N)
{
  const int w = threadIdx.x >> 6;
  const int lane = threadIdx.x & 63;
  const int quad = lane >> 4, l16 = lane & 15;
  const int d0 = w * 16;
  const int d = d0 + l16;

  B8u bw[3][4], bh[3][4];
#pragma unroll
  for (int g = 0; g < 3; ++g)
#pragma unroll
    for (int kc = 0; kc < 4; ++kc) {
      int j = (d0 + g * 128 + l16) * HID + kc * 32 + quad * 8;
      bw[g][kc].u = *(const uint4*)(Wcomb + j);
      bh[g][kc].u = *(const uint4*)(Whh16 + j);
    }
  const float bir = b_ih[d], biz = b_ih[d + 128], bin_ = b_ih[d + 256];
  const float bhr = b_hh[d], bhz = b_hh[d + 128], bhn = b_hh[d + 256];
  const float vr = bvec[d], vz = bvec[d + 128], vn = bvec[d + 256];

  const int nstrip = N >> 4;
  int s = blockIdx.x;
  if (s >= nstrip) return;

  B8u af[4], hf[4]; float hold[4], degf[4];
  {
    int n0 = s << 4;
    size_t arow = (size_t)(n0 + l16) * HID + quad * 8;
#pragma unroll
    for (int kc = 0; kc < 4; ++kc) {
      af[kc].u = *(const uint4*)(hs16 + arow + kc * 32);
      hf[kc].u = *(const uint4*)(hbc + arow + kc * 32);
    }
#pragma unroll
    for (int rg = 0; rg < 4; ++rg) {
      int n = n0 + quad * 4 + rg;
      hold[rg] = bf2f(hbc[(size_t)n * HID + d]);
      degf[rg] = (float)deg[n];
    }
  }

  while (true) {
    int ns = s + (int)gridDim.x;
    bool more = ns < nstrip;
    B8u af2[4], hf2[4]; float hold2[4], degf2[4];
    if (more) {
      int n0 = ns << 4;
      size_t arow = (size_t)(n0 + l16) * HID + quad * 8;
#pragma unroll
      for (int kc = 0; kc < 4; ++kc) {
        af2[kc].u = *(const uint4*)(hs16 + arow + kc * 32);
        hf2[kc].u = *(const uint4*)(hbc + arow + kc * 32);
      }
#pragma unroll
      for (int rg = 0; rg < 4; ++rg) {
        int n = n0 + quad * 4 + rg;
        hold2[rg] = bf2f(hbc[(size_t)n * HID + d]);
        degf2[rg] = (float)deg[n];
      }
    }

    f32x4 acc[6] = {};
#pragma unroll
    for (int kc = 0; kc < 4; ++kc)
#pragma unroll
      for (int g = 0; g < 3; ++g) {
        acc[g]     = __builtin_amdgcn_mfma_f32_16x16x32_bf16(af[kc].b, bw[g][kc].b, acc[g], 0, 0, 0);
        acc[3 + g] = __builtin_amdgcn_mfma_f32_16x16x32_bf16(hf[kc].b, bh[g][kc].b, acc[3 + g], 0, 0, 0);
      }

    int n0 = s << 4;
#pragma unroll
    for (int rg = 0; rg < 4; ++rg) {
      float ir = acc[0][rg] + degf[rg] * vr + bir;
      float iz = acc[1][rg] + degf[rg] * vz + biz;
      float in_ = acc[2][rg] + degf[rg] * vn + bin_;
      float hr = acc[3][rg] + bhr;
      float hz = acc[4][rg] + bhz;
      float hn = acc[5][rg] + bhn;
      float r = 1.f / (1.f + __expf(-(ir + hr)));
      float z = 1.f / (1.f + __expf(-(iz + hz)));
      float x2 = in_ + r * hn;
      float e2 = __expf(2.f * x2);
      float nv = 1.f - 2.f / (e2 + 1.f);   // tanh
      float hv = (1.f - z) * nv + z * hold[rg];
      hbn[(size_t)(n0 + quad * 4 + rg) * HID + d] = f2bf(hv);
    }

    if (!more) break;
    s = ns;
#pragma unroll
    for (int kc = 0; kc < 4; ++kc) { af[kc] = af2[kc]; hf[kc] = hf2[kc]; }
#pragma unroll
    for (int rg = 0; rg < 4; ++rg) { hold[rg] = hold2[rg]; degf[rg] = degf2[rg]; }
  }
}

// ---- per-graph counts from SORTED gid: binary search, no atomics
__global__ __launch_bounds__(64) void k_bounds(const int* __restrict__ gid,
                                               int* __restrict__ cnt, int N, int G) {
  int g = threadIdx.x;
  if (g >= G) return;
  int lo = 0, hi = N;
  while (lo < hi) { int mid = (lo + hi) >> 1; if (gid[mid] < g) lo = mid + 1; else hi = mid; }
  int lb0 = lo;
  lo = 0; hi = N;
  int g1 = g + 1;
  while (lo < hi) { int mid = (lo + hi) >> 1; if (gid[mid] < g1) lo = mid + 1; else hi = mid; }
  cnt[g] = lo - lb0;
}

// ---- pooling: graph_ids sorted -> run-length accumulate, few atomics
#define POOL_CHUNK 96
__global__ __launch_bounds__(128) void k_pool(const ushort* __restrict__ hb,
                                              const int* __restrict__ gid,
                                              float* __restrict__ hg, int N) {
  int d = threadIdx.x;
  int start = blockIdx.x * POOL_CHUNK;
  if (start >= N) return;
  int end = min(start + POOL_CHUNK, N);
  float acc = 0.f;
  int g = gid[start];
  for (int n = start; n < end; ++n) {
    int gn = gid[n];
    if (gn != g) { unsafeAtomicAdd(&hg[g * HID + d], acc); acc = 0.f; g = gn; }
    acc += fmaxf(bf2f(hb[(size_t)n * HID + d]), 0.f);   // relu
  }
  unsafeAtomicAdd(&hg[g * HID + d], acc);
}

__global__ __launch_bounds__(640) void k_cls(const float* __restrict__ hg,
                                             const int* __restrict__ cnt,
                                             const float* __restrict__ Wc,
                                             const float* __restrict__ bc,
                                             float* __restrict__ out, int G) {
  int t = threadIdx.x;
  if (t >= G * 10) return;
  int g = t / 10, c = t % 10;
  float inv = 1.f / fmaxf((float)cnt[g], 1.f);
  float acc = 0.f;
  for (int d = 0; d < HID; ++d) acc = fmaf(hg[g * HID + d], Wc[c * HID + d], acc);
  out[t] = acc * inv + bc[c];
}

extern "C" void kernel_launch(void* const* d_in, const int* in_sizes, int n_in,
                              void* d_out, int out_size, void* d_ws, size_t ws_size,
                              hipStream_t stream) {
  const int N = in_sizes[0];
  const int E = in_sizes[9];
  const float* m    = (const float*)d_in[0];
  const float* W_e  = (const float*)d_in[1];
  const float* b_e  = (const float*)d_in[2];
  const float* W_ih = (const float*)d_in[3];
  const float* b_ih = (const float*)d_in[4];
  const float* W_hh = (const float*)d_in[5];
  const float* b_hh = (const float*)d_in[6];
  const float* W_cls = (const float*)d_in[7];
  const float* b_cls = (const float*)d_in[8];
  const int* src = (const int*)d_in[9];
  const int* dst = (const int*)d_in[10];
  const int* gid = (const int*)d_in[11];
  const int G = out_size / 10;
  float* out = (float*)d_out;

  size_t off = 0;
  auto alloc = [&](size_t b) {
    char* p = (char*)d_ws + off;
    off += (b + 255) & ~(size_t)255;
    return (void*)p;
  };
  ushort* hb0    = (ushort*)alloc((size_t)N * HID * 2);
  ushort* hb1    = (ushort*)alloc((size_t)N * HID * 2);
  ushort* hs16   = (ushort*)alloc((size_t)N * HID * 2);
  int*    deg    = (int*)   alloc((size_t)N * 4);
  int*    rowptr = (int*)   alloc((size_t)(N + 1) * 4);
  int*    cursor = (int*)   alloc((size_t)N * 4);
  int*    csrc   = (int*)   alloc((size_t)E * 4);
  int*    bsum   = (int*)   alloc(64 * 4);
  int*    boff   = (int*)   alloc(64 * 4);
  ushort* Wcomb  = (ushort*)alloc((size_t)G3 * HID * 2);
  ushort* Whh16  = (ushort*)alloc((size_t)G3 * HID * 2);
  float*  bvec   = (float*) alloc((size_t)G3 * 4);
  float*  hg     = (float*) alloc((size_t)G * HID * 4);
  int*    cnt    = (int*)   alloc((size_t)G * 4);
  if (off > ws_size) return;   // workspace too small -> visible failure

  k_weights<<<2 * G3, HID, 0, stream>>>(W_e, b_e, W_ih, W_hh, Wcomb, Whh16, bvec);
  hipMemsetAsync(deg, 0, (size_t)N * 4, stream);
  hipMemsetAsync(cursor, 0, (size_t)N * 4, stream);
  k_deg<<<(E + 255) / 256, 256, 0, stream>>>(dst, deg, E);
  int B = (N + SCAN_TILE - 1) / SCAN_TILE;
  if (B <= 64) {
    k_scan1<<<B, 256, 0, stream>>>(deg, bsum, N);
    k_scan2<<<1, 64, 0, stream>>>(bsum, boff, rowptr, B, N);
    k_scan3<<<B, 256, 0, stream>>>(deg, boff, rowptr, N);
  } else {
    k_scan<<<1, 1024, 0, stream>>>(deg, rowptr, N);
  }
  k_fill<<<(E + 255) / 256, 256, 0, stream>>>(src, dst, rowptr, cursor, csrc, E);
  k_init<<<(N * HID + 255) / 256, 256, 0, stream>>>(m, hb0, N);

  ushort* hbc = hb0;
  ushort* hbn = hb1;
  for (int s = 0; s < TSTEPS; ++s) {
    k_gather<<<(N + 3) / 4, 256, 0, stream>>>(rowptr, csrc, hbc, hs16, N);
    int nstrip = N >> 4;
    int blocks = nstrip < 1024 ? nstrip : 1024;
    k_gru<<<blocks, 512, 0, stream>>>(hs16, hbc, hbn, Wcomb, Whh16, bvec, b_ih, b_hh, deg, N);
    ushort* t = hbc; hbc = hbn; hbn = t;
  }

  hipMemsetAsync(hg, 0, (size_t)G * HID * 4, stream);
  k_bounds<<<1, 64, 0, stream>>>(gid, cnt, N, G);
  k_pool<<<(N + POOL_CHUNK - 1) / POOL_CHUNK, HID, 0, stream>>>(hbc, gid, hg, N);
  k_cls<<<1, 640, 0, stream>>>(hg, cnt, W_cls, b_cls, out, G);
}

// Round 8
// 951.217 us; speedup vs baseline: 32.9159x; 1.1140x over previous
//
#include <hip/hip_runtime.h>

#define HID 128
#define G3  384   // 3*HID
#define TSTEPS 5
#define BSHIFT 9          // 512 nodes per bucket
#define BNODES (1 << BSHIFT)
#define MAXBUK 256        // supports N up to 128k
#define PART_EPB 8192     // edges per k_part block

typedef unsigned int  uint;
typedef unsigned short ushort;

typedef float  f32x4  __attribute__((ext_vector_type(4)));
typedef __bf16 bf16x8 __attribute__((ext_vector_type(8)));

union B8u { uint4 u; bf16x8 b; ushort s[8]; };

static __device__ inline ushort f2bf(float f) {
  uint u = __float_as_uint(f);
  uint r = u + 0x7fffu + ((u >> 16) & 1u);   // RTN-even
  return (ushort)(r >> 16);
}
static __device__ inline float bf2f(ushort s) {
  return __uint_as_float(((uint)s) << 16);
}

// ---- once per call: W_comb = W_ih @ W_e (bf16), bvec = W_ih @ b_e, W_hh -> bf16
__global__ __launch_bounds__(128) void k_weights(
    const float* __restrict__ W_e, const float* __restrict__ b_e,
    const float* __restrict__ W_ih, const float* __restrict__ W_hh,
    ushort* __restrict__ Wcomb, ushort* __restrict__ Whh16, float* __restrict__ bvec)
{
  int j = blockIdx.x, t = threadIdx.x;
  if (j < G3) {
    __shared__ float row[HID];
    row[t] = W_ih[j * HID + t];
    __syncthreads();
    float acc = 0.f;
    for (int k = 0; k < HID; ++k) acc = fmaf(row[k], W_e[k * HID + t], acc);
    Wcomb[j * HID + t] = f2bf(acc);
    if (t == 0) {
      float b = 0.f;
      for (int k = 0; k < HID; ++k) b += row[k] * b_e[k];
      bvec[j] = b;
    }
  } else {
    int j2 = j - G3;
    Whh16[j2 * HID + t] = f2bf(W_hh[j2 * HID + t]);
  }
}

// ---- CSR build, stage 1: bucket histogram of dst (LDS-aggregated)
__global__ __launch_bounds__(256) void k_bh(const int* __restrict__ dst,
                                            int* __restrict__ bhist, int E) {
  __shared__ int lh[MAXBUK];
  int t = threadIdx.x;
  if (t < MAXBUK) lh[t] = 0;
  __syncthreads();
  for (int e = blockIdx.x * 256 + t; e < E; e += gridDim.x * 256)
    atomicAdd(&lh[dst[e] >> BSHIFT], 1);
  __syncthreads();
  if (t < MAXBUK && lh[t]) atomicAdd(&bhist[t], lh[t]);
}

// ---- stage 2: serial scan of <=256 bucket counts (trivial size)
__global__ __launch_bounds__(256) void k_bsc(const int* __restrict__ bhist,
                                             int* __restrict__ bbase,
                                             int* __restrict__ gcur,
                                             int* __restrict__ rowptr, int E, int N) {
  __shared__ int ls[MAXBUK];
  int t = threadIdx.x;
  ls[t] = bhist[t];
  __syncthreads();
  if (t == 0) {
    int run = 0;
    for (int i = 0; i < MAXBUK; ++i) {
      bbase[i] = run; gcur[i] = run; run += ls[i];
    }
    bbase[MAXBUK] = run;
    rowptr[N] = E;
  }
}

// ---- stage 3: partition packed (dl<<20)|src into bucket-grouped ebuf.
// Per-block LDS hist -> one global reservation atomic per (block,bucket) ->
// block-contiguous chunk writes (active lines stay L2-resident & exclusive).
__global__ __launch_bounds__(256) void k_part(
    const int* __restrict__ src, const int* __restrict__ dst,
    int* __restrict__ gcur, uint* __restrict__ ebuf, int E) {
  __shared__ int lh[MAXBUK], lbase[MAXBUK], lcur[MAXBUK];
  int t = threadIdx.x;
  int base = blockIdx.x * PART_EPB;
  if (t < MAXBUK) lh[t] = 0;
  __syncthreads();
#pragma unroll 4
  for (int j = 0; j < PART_EPB / 256; ++j) {
    int e = base + j * 256 + t;
    if (e < E) atomicAdd(&lh[dst[e] >> BSHIFT], 1);
  }
  __syncthreads();
  if (t < MAXBUK) {
    lbase[t] = lh[t] ? atomicAdd(&gcur[t], lh[t]) : 0;
    lcur[t] = 0;
  }
  __syncthreads();
#pragma unroll 4
  for (int j = 0; j < PART_EPB / 256; ++j) {
    int e = base + j * 256 + t;
    if (e < E) {
      int d = dst[e];
      int b = d >> BSHIFT;
      int p = atomicAdd(&lcur[b], 1);
      ebuf[lbase[b] + p] = (uint)src[e] | ((uint)(d & (BNODES - 1)) << 20);
    }
  }
}

// ---- stage 4: one block per bucket. LDS per-node hist -> scan -> writes
// rowptr & deg segments directly, then LDS-cursor scatter of csrc into the
// bucket's contiguous (L2-hot) region.
__global__ __launch_bounds__(256) void k_fill2(
    const uint* __restrict__ ebuf, const int* __restrict__ bbase,
    int* __restrict__ csrc, int* __restrict__ rowptr, int* __restrict__ deg, int N) {
  __shared__ int hcnt[BNODES];
  __shared__ int wls[4];
  int t = threadIdx.x;
  int b = blockIdx.x;
  int ebeg = bbase[b], eend = bbase[b + 1];
  for (int i = t; i < BNODES; i += 256) hcnt[i] = 0;
  __syncthreads();
  for (int e = ebeg + t; e < eend; e += 256)
    atomicAdd(&hcnt[ebuf[e] >> 20], 1);
  __syncthreads();
  // exclusive scan of BNODES counters (2 per thread at BNODES=512)
  const int PER = BNODES / 256;
  int lane = t & 63, wv = t >> 6;
  int x[PER]; int s = 0;
#pragma unroll
  for (int i = 0; i < PER; ++i) { x[i] = hcnt[PER * t + i]; s += x[i]; }
  int incl = s;
#pragma unroll
  for (int off = 1; off < 64; off <<= 1) {
    int u = __shfl_up(incl, off, 64);
    if (lane >= off) incl += u;
  }
  if (lane == 63) wls[wv] = incl;
  __syncthreads();
  int wbase = 0;
  for (int i = 0; i < wv; ++i) wbase += wls[i];
  int run = wbase + incl - s;
#pragma unroll
  for (int i = 0; i < PER; ++i) {
    int node = (b << BSHIFT) + PER * t + i;
    hcnt[PER * t + i] = run;            // exclusive prefix -> cursor start
    if (node < N) { rowptr[node] = ebeg + run; deg[node] = x[i]; }
    run += x[i];
  }
  __syncthreads();
  for (int e = ebeg + t; e < eend; e += 256) {
    uint v = ebuf[e];
    int p = atomicAdd(&hcnt[v >> 20], 1);
    csrc[ebeg + p] = (int)(v & 0xFFFFFu);
  }
}

__global__ void k_init(const float* __restrict__ m, ushort* __restrict__ hb, int N) {
  int idx = blockIdx.x * 256 + threadIdx.x;
  if (idx >= N * HID) return;
  int d = idx & (HID - 1);
  float v = (d == 0) ? m[idx >> 7] : 0.f;
  hb[idx] = f2bf(v);
}

// ---- gather: hs16[v] = bf16( sum_{u in N_in(v)} h[u] ); one wave per node.
// Wave split into 4 x 16-lane groups: group g handles edge slot g with
// dwordx4 row loads (lane i owns dims [8i,8i+8)). One unrolled iteration
// puts 16 edges (4 KB) in flight. Cross-group reduce via shfl_xor(16,32).
__global__ __launch_bounds__(256) void k_gather(
    const int* __restrict__ rowptr, const int* __restrict__ csrc,
    const ushort* __restrict__ hb, ushort* __restrict__ hs16, int N)
{
  int v = blockIdx.x * 4 + (threadIdx.x >> 6);
  if (v >= N) return;
  int lane = threadIdx.x & 63;
  int g = lane >> 4;        // edge slot 0..3
  int i = lane & 15;        // 16B chunk of row
  int beg = rowptr[v], end = rowptr[v + 1];
  float acc[8] = {0.f, 0.f, 0.f, 0.f, 0.f, 0.f, 0.f, 0.f};
  int e = beg;
  for (; e + 16 <= end; e += 16) {      // 16 edges in flight
    int s0 = csrc[e + g];
    int s1 = csrc[e + 4 + g];
    int s2 = csrc[e + 8 + g];
    int s3 = csrc[e + 12 + g];
    B8u w0; w0.u = *(const uint4*)(hb + (size_t)s0 * HID + i * 8);
    B8u w1; w1.u = *(const uint4*)(hb + (size_t)s1 * HID + i * 8);
    B8u w2; w2.u = *(const uint4*)(hb + (size_t)s2 * HID + i * 8);
    B8u w3; w3.u = *(const uint4*)(hb + (size_t)s3 * HID + i * 8);
#pragma unroll
    for (int j = 0; j < 8; ++j)
      acc[j] += (bf2f(w0.s[j]) + bf2f(w1.s[j])) + (bf2f(w2.s[j]) + bf2f(w3.s[j]));
  }
  for (; e < end; e += 4) {             // predicated 4-edge tail
    int ee = e + g;
    if (ee < end) {
      int s0 = csrc[ee];
      B8u w; w.u = *(const uint4*)(hb + (size_t)s0 * HID + i * 8);
#pragma unroll
      for (int j = 0; j < 8; ++j) acc[j] += bf2f(w.s[j]);
    }
  }
#pragma unroll
  for (int j = 0; j < 8; ++j) {
    acc[j] += __shfl_xor(acc[j], 16, 64);
    acc[j] += __shfl_xor(acc[j], 32, 64);
  }
  if (g == 0) {
    uint4 ov;
    ov.x = ((uint)f2bf(acc[1]) << 16) | (uint)f2bf(acc[0]);
    ov.y = ((uint)f2bf(acc[3]) << 16) | (uint)f2bf(acc[2]);
    ov.z = ((uint)f2bf(acc[5]) << 16) | (uint)f2bf(acc[4]);
    ov.w = ((uint)f2bf(acc[7]) << 16) | (uint)f2bf(acc[6]);
    *(uint4*)(hs16 + (size_t)v * HID + i * 8) = ov;
  }
}

// ---- fused GEMM + GRU. Weights live in VGPRs for the whole kernel; block
// grid-strides over 16-node strips with manual double-buffered A/epilogue
// loads. State is bf16-only; hb ping-pongs across steps; no barriers.
__global__ __launch_bounds__(512, 2) void k_gru(
    const ushort* __restrict__ hs16,
    const ushort* __restrict__ hbc, ushort* __restrict__ hbn,
    const ushort* __restrict__ Wcomb, const ushort* __restrict__ Whh16,
    const float* __restrict__ bvec, const float* __restrict__ b_ih,
    const float* __restrict__ b_hh, const int* __restrict__ deg, int N)
{
  const int w = threadIdx.x >> 6;
  const int lane = threadIdx.x & 63;
  const int quad = lane >> 4, l16 = lane & 15;
  const int d0 = w * 16;
  const int d = d0 + l16;

  B8u bw[3][4], bh[3][4];
#pragma unroll
  for (int g = 0; g < 3; ++g)
#pragma unroll
    for (int kc = 0; kc < 4; ++kc) {
      int j = (d0 + g * 128 + l16) * HID + kc * 32 + quad * 8;
      bw[g][kc].u = *(const uint4*)(Wcomb + j);
      bh[g][kc].u = *(const uint4*)(Whh16 + j);
    }
  const float bir = b_ih[d], biz = b_ih[d + 128], bin_ = b_ih[d + 256];
  const float bhr = b_hh[d], bhz = b_hh[d + 128], bhn = b_hh[d + 256];
  const float vr = bvec[d], vz = bvec[d + 128], vn = bvec[d + 256];

  const int nstrip = N >> 4;
  int s = blockIdx.x;
  if (s >= nstrip) return;

  B8u af[4], hf[4]; float hold[4], degf[4];
  {
    int n0 = s << 4;
    size_t arow = (size_t)(n0 + l16) * HID + quad * 8;
#pragma unroll
    for (int kc = 0; kc < 4; ++kc) {
      af[kc].u = *(const uint4*)(hs16 + arow + kc * 32);
      hf[kc].u = *(const uint4*)(hbc + arow + kc * 32);
    }
#pragma unroll
    for (int rg = 0; rg < 4; ++rg) {
      int n = n0 + quad * 4 + rg;
      hold[rg] = bf2f(hbc[(size_t)n * HID + d]);
      degf[rg] = (float)deg[n];
    }
  }

  while (true) {
    int ns = s + (int)gridDim.x;
    bool more = ns < nstrip;
    B8u af2[4], hf2[4]; float hold2[4], degf2[4];
    if (more) {
      int n0 = ns << 4;
      size_t arow = (size_t)(n0 + l16) * HID + quad * 8;
#pragma unroll
      for (int kc = 0; kc < 4; ++kc) {
        af2[kc].u = *(const uint4*)(hs16 + arow + kc * 32);
        hf2[kc].u = *(const uint4*)(hbc + arow + kc * 32);
      }
#pragma unroll
      for (int rg = 0; rg < 4; ++rg) {
        int n = n0 + quad * 4 + rg;
        hold2[rg] = bf2f(hbc[(size_t)n * HID + d]);
        degf2[rg] = (float)deg[n];
      }
    }

    f32x4 acc[6] = {};
#pragma unroll
    for (int kc = 0; kc < 4; ++kc)
#pragma unroll
      for (int g = 0; g < 3; ++g) {
        acc[g]     = __builtin_amdgcn_mfma_f32_16x16x32_bf16(af[kc].b, bw[g][kc].b, acc[g], 0, 0, 0);
        acc[3 + g] = __builtin_amdgcn_mfma_f32_16x16x32_bf16(hf[kc].b, bh[g][kc].b, acc[3 + g], 0, 0, 0);
      }

    int n0 = s << 4;
#pragma unroll
    for (int rg = 0; rg < 4; ++rg) {
      float ir = acc[0][rg] + degf[rg] * vr + bir;
      float iz = acc[1][rg] + degf[rg] * vz + biz;
      float in_ = acc[2][rg] + degf[rg] * vn + bin_;
      float hr = acc[3][rg] + bhr;
      float hz = acc[4][rg] + bhz;
      float hn = acc[5][rg] + bhn;
      float r = 1.f / (1.f + __expf(-(ir + hr)));
      float z = 1.f / (1.f + __expf(-(iz + hz)));
      float x2 = in_ + r * hn;
      float e2 = __expf(2.f * x2);
      float nv = 1.f - 2.f / (e2 + 1.f);   // tanh
      float hv = (1.f - z) * nv + z * hold[rg];
      hbn[(size_t)(n0 + quad * 4 + rg) * HID + d] = f2bf(hv);
    }

    if (!more) break;
    s = ns;
#pragma unroll
    for (int kc = 0; kc < 4; ++kc) { af[kc] = af2[kc]; hf[kc] = hf2[kc]; }
#pragma unroll
    for (int rg = 0; rg < 4; ++rg) { hold[rg] = hold2[rg]; degf[rg] = degf2[rg]; }
  }
}

// ---- per-graph counts from SORTED gid: binary search, no atomics
__global__ __launch_bounds__(64) void k_bounds(const int* __restrict__ gid,
                                               int* __restrict__ cnt, int N, int G) {
  int g = threadIdx.x;
  if (g >= G) return;
  int lo = 0, hi = N;
  while (lo < hi) { int mid = (lo + hi) >> 1; if (gid[mid] < g) lo = mid + 1; else hi = mid; }
  int lb0 = lo;
  lo = 0; hi = N;
  int g1 = g + 1;
  while (lo < hi) { int mid = (lo + hi) >> 1; if (gid[mid] < g1) lo = mid + 1; else hi = mid; }
  cnt[g] = lo - lb0;
}

// ---- pooling: graph_ids sorted -> run-length accumulate, few atomics
#define POOL_CHUNK 96
__global__ __launch_bounds__(128) void k_pool(const ushort* __restrict__ hb,
                                              const int* __restrict__ gid,
                                              float* __restrict__ hg, int N) {
  int d = threadIdx.x;
  int start = blockIdx.x * POOL_CHUNK;
  if (start >= N) return;
  int end = min(start + POOL_CHUNK, N);
  float acc = 0.f;
  int g = gid[start];
  for (int n = start; n < end; ++n) {
    int gn = gid[n];
    if (gn != g) { unsafeAtomicAdd(&hg[g * HID + d], acc); acc = 0.f; g = gn; }
    acc += fmaxf(bf2f(hb[(size_t)n * HID + d]), 0.f);   // relu
  }
  unsafeAtomicAdd(&hg[g * HID + d], acc);
}

__global__ __launch_bounds__(640) void k_cls(const float* __restrict__ hg,
                                             const int* __restrict__ cnt,
                                             const float* __restrict__ Wc,
                                             const float* __restrict__ bc,
                                             float* __restrict__ out, int G) {
  int t = threadIdx.x;
  if (t >= G * 10) return;
  int g = t / 10, c = t % 10;
  float inv = 1.f / fmaxf((float)cnt[g], 1.f);
  float acc = 0.f;
  for (int d = 0; d < HID; ++d) acc = fmaf(hg[g * HID + d], Wc[c * HID + d], acc);
  out[t] = acc * inv + bc[c];
}

extern "C" void kernel_launch(void* const* d_in, const int* in_sizes, int n_in,
                              void* d_out, int out_size, void* d_ws, size_t ws_size,
                              hipStream_t stream) {
  const int N = in_sizes[0];
  const int E = in_sizes[9];
  const float* m    = (const float*)d_in[0];
  const float* W_e  = (const float*)d_in[1];
  const float* b_e  = (const float*)d_in[2];
  const float* W_ih = (const float*)d_in[3];
  const float* b_ih = (const float*)d_in[4];
  const float* W_hh = (const float*)d_in[5];
  const float* b_hh = (const float*)d_in[6];
  const float* W_cls = (const float*)d_in[7];
  const float* b_cls = (const float*)d_in[8];
  const int* src = (const int*)d_in[9];
  const int* dst = (const int*)d_in[10];
  const int* gid = (const int*)d_in[11];
  const int G = out_size / 10;
  float* out = (float*)d_out;

  size_t off = 0;
  auto alloc = [&](size_t b) {
    char* p = (char*)d_ws + off;
    off += (b + 255) & ~(size_t)255;
    return (void*)p;
  };
  ushort* hb0    = (ushort*)alloc((size_t)N * HID * 2);
  ushort* hb1    = (ushort*)alloc((size_t)N * HID * 2);
  ushort* hs16   = (ushort*)alloc((size_t)N * HID * 2);
  int*    deg    = (int*)   alloc((size_t)N * 4);
  int*    rowptr = (int*)   alloc((size_t)(N + 1) * 4);
  int*    csrc   = (int*)   alloc((size_t)E * 4);
  uint*   ebuf   = (uint*)  alloc((size_t)E * 4);
  int*    bhist  = (int*)   alloc((size_t)MAXBUK * 4);
  int*    bbase  = (int*)   alloc((size_t)(MAXBUK + 1) * 4);
  int*    gcur   = (int*)   alloc((size_t)MAXBUK * 4);
  ushort* Wcomb  = (ushort*)alloc((size_t)G3 * HID * 2);
  ushort* Whh16  = (ushort*)alloc((size_t)G3 * HID * 2);
  float*  bvec   = (float*) alloc((size_t)G3 * 4);
  float*  hg     = (float*) alloc((size_t)G * HID * 4);
  int*    cnt    = (int*)   alloc((size_t)G * 4);
  if (off > ws_size) return;   // workspace too small -> visible failure

  const int NBUK = (N + BNODES - 1) >> BSHIFT;   // 196 at N=100k (<= MAXBUK)

  k_weights<<<2 * G3, HID, 0, stream>>>(W_e, b_e, W_ih, W_hh, Wcomb, Whh16, bvec);
  hipMemsetAsync(bhist, 0, (size_t)MAXBUK * 4, stream);
  k_bh<<<256, 256, 0, stream>>>(dst, bhist, E);
  k_bsc<<<1, MAXBUK, 0, stream>>>(bhist, bbase, gcur, rowptr, E, N);
  k_part<<<(E + PART_EPB - 1) / PART_EPB, 256, 0, stream>>>(src, dst, gcur, ebuf, E);
  k_fill2<<<NBUK, 256, 0, stream>>>(ebuf, bbase, csrc, rowptr, deg, N);
  k_init<<<(N * HID + 255) / 256, 256, 0, stream>>>(m, hb0, N);

  ushort* hbc = hb0;
  ushort* hbn = hb1;
  for (int s = 0; s < TSTEPS; ++s) {
    k_gather<<<(N + 3) / 4, 256, 0, stream>>>(rowptr, csrc, hbc, hs16, N);
    int nstrip = N >> 4;
    int blocks = nstrip < 1024 ? nstrip : 1024;
    k_gru<<<blocks, 512, 0, stream>>>(hs16, hbc, hbn, Wcomb, Whh16, bvec, b_ih, b_hh, deg, N);
    ushort* t = hbc; hbc = hbn; hbn = t;
  }

  hipMemsetAsync(hg, 0, (size_t)G * HID * 4, stream);
  k_bounds<<<1, 64, 0, stream>>>(gid, cnt, N, G);
  k_pool<<<(N + POOL_CHUNK - 1) / POOL_CHUNK, HID, 0, stream>>>(hbc, gid, hg, N);
  k_cls<<<1, 640, 0, stream>>>(hg, cnt, W_cls, b_cls, out, G);
}

// Round 9
// 927.523 us; speedup vs baseline: 33.7567x; 1.0255x over previous
//
#include <hip/hip_runtime.h>

#define HID 128
#define G3  384   // 3*HID
#define TSTEPS 5
#define BSHIFT 9          // 512 nodes per bucket
#define BNODES (1 << BSHIFT)
#define MAXBUK 256        // supports N up to 128k
#define PART_EPB 8192     // edges per k_part block

typedef unsigned int  uint;
typedef unsigned short ushort;

typedef float  f32x4  __attribute__((ext_vector_type(4)));
typedef __bf16 bf16x8 __attribute__((ext_vector_type(8)));

union B8u { uint4 u; bf16x8 b; ushort s[8]; };

static __device__ inline ushort f2bf(float f) {
  uint u = __float_as_uint(f);
  uint r = u + 0x7fffu + ((u >> 16) & 1u);   // RTN-even
  return (ushort)(r >> 16);
}
static __device__ inline float bf2f(ushort s) {
  return __uint_as_float(((uint)s) << 16);
}

// ---- once per call: W_comb = W_ih @ W_e (bf16), bvec = W_ih @ b_e, W_hh -> bf16
__global__ __launch_bounds__(128) void k_weights(
    const float* __restrict__ W_e, const float* __restrict__ b_e,
    const float* __restrict__ W_ih, const float* __restrict__ W_hh,
    ushort* __restrict__ Wcomb, ushort* __restrict__ Whh16, float* __restrict__ bvec)
{
  int j = blockIdx.x, t = threadIdx.x;
  if (j < G3) {
    __shared__ float row[HID];
    row[t] = W_ih[j * HID + t];
    __syncthreads();
    float acc = 0.f;
    for (int k = 0; k < HID; ++k) acc = fmaf(row[k], W_e[k * HID + t], acc);
    Wcomb[j * HID + t] = f2bf(acc);
    if (t == 0) {
      float b = 0.f;
      for (int k = 0; k < HID; ++k) b += row[k] * b_e[k];
      bvec[j] = b;
    }
  } else {
    int j2 = j - G3;
    Whh16[j2 * HID + t] = f2bf(W_hh[j2 * HID + t]);
  }
}

// ---- CSR build, stage 1: bucket histogram of dst (LDS-aggregated)
__global__ __launch_bounds__(256) void k_bh(const int* __restrict__ dst,
                                            int* __restrict__ bhist, int E) {
  __shared__ int lh[MAXBUK];
  int t = threadIdx.x;
  if (t < MAXBUK) lh[t] = 0;
  __syncthreads();
  for (int e = blockIdx.x * 256 + t; e < E; e += gridDim.x * 256)
    atomicAdd(&lh[dst[e] >> BSHIFT], 1);
  __syncthreads();
  if (t < MAXBUK && lh[t]) atomicAdd(&bhist[t], lh[t]);
}

// ---- stage 2: serial scan of <=256 bucket counts (trivial size)
__global__ __launch_bounds__(256) void k_bsc(const int* __restrict__ bhist,
                                             int* __restrict__ bbase,
                                             int* __restrict__ gcur,
                                             int* __restrict__ rowptr, int E, int N) {
  __shared__ int ls[MAXBUK];
  int t = threadIdx.x;
  ls[t] = bhist[t];
  __syncthreads();
  if (t == 0) {
    int run = 0;
    for (int i = 0; i < MAXBUK; ++i) {
      bbase[i] = run; gcur[i] = run; run += ls[i];
    }
    bbase[MAXBUK] = run;
    rowptr[N] = E;
  }
}

// ---- stage 3: partition packed (dl<<20)|src into bucket-grouped ebuf.
__global__ __launch_bounds__(256) void k_part(
    const int* __restrict__ src, const int* __restrict__ dst,
    int* __restrict__ gcur, uint* __restrict__ ebuf, int E) {
  __shared__ int lh[MAXBUK], lbase[MAXBUK], lcur[MAXBUK];
  int t = threadIdx.x;
  int base = blockIdx.x * PART_EPB;
  if (t < MAXBUK) lh[t] = 0;
  __syncthreads();
#pragma unroll 4
  for (int j = 0; j < PART_EPB / 256; ++j) {
    int e = base + j * 256 + t;
    if (e < E) atomicAdd(&lh[dst[e] >> BSHIFT], 1);
  }
  __syncthreads();
  if (t < MAXBUK) {
    lbase[t] = lh[t] ? atomicAdd(&gcur[t], lh[t]) : 0;
    lcur[t] = 0;
  }
  __syncthreads();
#pragma unroll 4
  for (int j = 0; j < PART_EPB / 256; ++j) {
    int e = base + j * 256 + t;
    if (e < E) {
      int d = dst[e];
      int b = d >> BSHIFT;
      int p = atomicAdd(&lcur[b], 1);
      ebuf[lbase[b] + p] = (uint)src[e] | ((uint)(d & (BNODES - 1)) << 20);
    }
  }
}

// ---- stage 4: one block per bucket: LDS hist -> scan -> rowptr/deg -> scatter
__global__ __launch_bounds__(256) void k_fill2(
    const uint* __restrict__ ebuf, const int* __restrict__ bbase,
    int* __restrict__ csrc, int* __restrict__ rowptr, int* __restrict__ deg, int N) {
  __shared__ int hcnt[BNODES];
  __shared__ int wls[4];
  int t = threadIdx.x;
  int b = blockIdx.x;
  int ebeg = bbase[b], eend = bbase[b + 1];
  for (int i = t; i < BNODES; i += 256) hcnt[i] = 0;
  __syncthreads();
  for (int e = ebeg + t; e < eend; e += 256)
    atomicAdd(&hcnt[ebuf[e] >> 20], 1);
  __syncthreads();
  const int PER = BNODES / 256;
  int lane = t & 63, wv = t >> 6;
  int x[PER]; int s = 0;
#pragma unroll
  for (int i = 0; i < PER; ++i) { x[i] = hcnt[PER * t + i]; s += x[i]; }
  int incl = s;
#pragma unroll
  for (int off = 1; off < 64; off <<= 1) {
    int u = __shfl_up(incl, off, 64);
    if (lane >= off) incl += u;
  }
  if (lane == 63) wls[wv] = incl;
  __syncthreads();
  int wbase = 0;
  for (int i = 0; i < wv; ++i) wbase += wls[i];
  int run = wbase + incl - s;
#pragma unroll
  for (int i = 0; i < PER; ++i) {
    int node = (b << BSHIFT) + PER * t + i;
    hcnt[PER * t + i] = run;
    if (node < N) { rowptr[node] = ebeg + run; deg[node] = x[i]; }
    run += x[i];
  }
  __syncthreads();
  for (int e = ebeg + t; e < eend; e += 256) {
    uint v = ebuf[e];
    int p = atomicAdd(&hcnt[v >> 20], 1);
    csrc[ebeg + p] = (int)(v & 0xFFFFFu);
  }
}

__global__ void k_init(const float* __restrict__ m, ushort* __restrict__ hb, int N) {
  int idx = blockIdx.x * 256 + threadIdx.x;
  if (idx >= N * HID) return;
  int d = idx & (HID - 1);
  float v = (d == 0) ? m[idx >> 7] : 0.f;
  hb[idx] = f2bf(v);
}

// ---- gather: hs16[v] = bf16( sum_{u in N_in(v)} h[u] ); one wave per node.
__global__ __launch_bounds__(256) void k_gather(
    const int* __restrict__ rowptr, const int* __restrict__ csrc,
    const ushort* __restrict__ hb, ushort* __restrict__ hs16, int N)
{
  int v = blockIdx.x * 4 + (threadIdx.x >> 6);
  if (v >= N) return;
  int lane = threadIdx.x & 63;
  int g = lane >> 4;        // edge slot 0..3
  int i = lane & 15;        // 16B chunk of row
  int beg = rowptr[v], end = rowptr[v + 1];
  float acc[8] = {0.f, 0.f, 0.f, 0.f, 0.f, 0.f, 0.f, 0.f};
  int e = beg;
  for (; e + 16 <= end; e += 16) {      // 16 edges in flight
    int s0 = csrc[e + g];
    int s1 = csrc[e + 4 + g];
    int s2 = csrc[e + 8 + g];
    int s3 = csrc[e + 12 + g];
    B8u w0; w0.u = *(const uint4*)(hb + (size_t)s0 * HID + i * 8);
    B8u w1; w1.u = *(const uint4*)(hb + (size_t)s1 * HID + i * 8);
    B8u w2; w2.u = *(const uint4*)(hb + (size_t)s2 * HID + i * 8);
    B8u w3; w3.u = *(const uint4*)(hb + (size_t)s3 * HID + i * 8);
#pragma unroll
    for (int j = 0; j < 8; ++j)
      acc[j] += (bf2f(w0.s[j]) + bf2f(w1.s[j])) + (bf2f(w2.s[j]) + bf2f(w3.s[j]));
  }
  for (; e < end; e += 4) {             // predicated 4-edge tail
    int ee = e + g;
    if (ee < end) {
      int s0 = csrc[ee];
      B8u w; w.u = *(const uint4*)(hb + (size_t)s0 * HID + i * 8);
#pragma unroll
      for (int j = 0; j < 8; ++j) acc[j] += bf2f(w.s[j]);
    }
  }
#pragma unroll
  for (int j = 0; j < 8; ++j) {
    acc[j] += __shfl_xor(acc[j], 16, 64);
    acc[j] += __shfl_xor(acc[j], 32, 64);
  }
  if (g == 0) {
    uint4 ov;
    ov.x = ((uint)f2bf(acc[1]) << 16) | (uint)f2bf(acc[0]);
    ov.y = ((uint)f2bf(acc[3]) << 16) | (uint)f2bf(acc[2]);
    ov.z = ((uint)f2bf(acc[5]) << 16) | (uint)f2bf(acc[4]);
    ov.w = ((uint)f2bf(acc[7]) << 16) | (uint)f2bf(acc[6]);
    *(uint4*)(hs16 + (size_t)v * HID + i * 8) = ov;
  }
}

// ---- fused GEMM + GRU helpers (forced inline; buffers passed by reference)
struct GruCtx {
  const ushort* hs16; const ushort* hbc; ushort* hbn; const int* deg;
  int l16, quad, d;
  float bir, biz, bin_, bhr, bhz, bhn, vr, vz, vn;
};

static __device__ __forceinline__ void gru_load(
    const GruCtx& c, int s, B8u af[4], B8u hf[4], float hold[4], float degf[4]) {
  int n0 = s << 4;
  size_t arow = (size_t)(n0 + c.l16) * HID + c.quad * 8;
#pragma unroll
  for (int kc = 0; kc < 4; ++kc) {
    af[kc].u = *(const uint4*)(c.hs16 + arow + kc * 32);
    hf[kc].u = *(const uint4*)(c.hbc + arow + kc * 32);
  }
#pragma unroll
  for (int rg = 0; rg < 4; ++rg) {
    int n = n0 + c.quad * 4 + rg;
    hold[rg] = bf2f(c.hbc[(size_t)n * HID + c.d]);
    degf[rg] = (float)c.deg[n];
  }
}

static __device__ __forceinline__ void gru_compute(
    const GruCtx& c, int s, const B8u af[4], const B8u hf[4],
    const float hold[4], const float degf[4],
    const B8u bw[3][4], const B8u bh[3][4]) {
  f32x4 acc[6] = {};
#pragma unroll
  for (int kc = 0; kc < 4; ++kc)
#pragma unroll
    for (int g = 0; g < 3; ++g) {
      acc[g]     = __builtin_amdgcn_mfma_f32_16x16x32_bf16(af[kc].b, bw[g][kc].b, acc[g], 0, 0, 0);
      acc[3 + g] = __builtin_amdgcn_mfma_f32_16x16x32_bf16(hf[kc].b, bh[g][kc].b, acc[3 + g], 0, 0, 0);
    }
  int n0 = s << 4;
#pragma unroll
  for (int rg = 0; rg < 4; ++rg) {
    float ir = acc[0][rg] + degf[rg] * c.vr + c.bir;
    float iz = acc[1][rg] + degf[rg] * c.vz + c.biz;
    float in_ = acc[2][rg] + degf[rg] * c.vn + c.bin_;
    float hr = acc[3][rg] + c.bhr;
    float hz = acc[4][rg] + c.bhz;
    float hn = acc[5][rg] + c.bhn;
    float r = __builtin_amdgcn_rcpf(1.f + __expf(-(ir + hr)));
    float z = __builtin_amdgcn_rcpf(1.f + __expf(-(iz + hz)));
    float x2 = in_ + r * hn;
    float e2 = __expf(2.f * x2);
    float nv = 1.f - 2.f * __builtin_amdgcn_rcpf(e2 + 1.f);   // tanh
    float hv = (1.f - z) * nv + z * hold[rg];
    c.hbn[(size_t)(n0 + c.quad * 4 + rg) * HID + c.d] = f2bf(hv);
  }
}

// Weights persistent in regs; grid-stride over 16-node strips with an
// explicitly unrolled 2-body ping-pong (no buffer-rotate movs).
__global__ __launch_bounds__(512, 2) void k_gru(
    const ushort* __restrict__ hs16,
    const ushort* __restrict__ hbc, ushort* __restrict__ hbn,
    const ushort* __restrict__ Wcomb, const ushort* __restrict__ Whh16,
    const float* __restrict__ bvec, const float* __restrict__ b_ih,
    const float* __restrict__ b_hh, const int* __restrict__ deg, int N)
{
  const int w = threadIdx.x >> 6;
  const int lane = threadIdx.x & 63;
  const int quad = lane >> 4, l16 = lane & 15;
  const int d0 = w * 16;
  const int d = d0 + l16;

  B8u bw[3][4], bh[3][4];
#pragma unroll
  for (int g = 0; g < 3; ++g)
#pragma unroll
    for (int kc = 0; kc < 4; ++kc) {
      int j = (d0 + g * 128 + l16) * HID + kc * 32 + quad * 8;
      bw[g][kc].u = *(const uint4*)(Wcomb + j);
      bh[g][kc].u = *(const uint4*)(Whh16 + j);
    }

  GruCtx c;
  c.hs16 = hs16; c.hbc = hbc; c.hbn = hbn; c.deg = deg;
  c.l16 = l16; c.quad = quad; c.d = d;
  c.bir = b_ih[d]; c.biz = b_ih[d + 128]; c.bin_ = b_ih[d + 256];
  c.bhr = b_hh[d]; c.bhz = b_hh[d + 128]; c.bhn = b_hh[d + 256];
  c.vr = bvec[d]; c.vz = bvec[d + 128]; c.vn = bvec[d + 256];

  const int nstrip = N >> 4;
  const int G = (int)gridDim.x;
  int s = blockIdx.x;
  if (s >= nstrip) return;

  B8u afA[4], hfA[4], afB[4], hfB[4];
  float holdA[4], degA[4], holdB[4], degB[4];
  gru_load(c, s, afA, hfA, holdA, degA);

  while (true) {
    int ns = s + G;                 // body A: compute A-bufs, prefetch into B
    bool more = ns < nstrip;
    if (more) gru_load(c, ns, afB, hfB, holdB, degB);
    gru_compute(c, s, afA, hfA, holdA, degA, bw, bh);
    if (!more) break;
    s = ns;
    ns = s + G;                     // body B: compute B-bufs, prefetch into A
    more = ns < nstrip;
    if (more) gru_load(c, ns, afA, hfA, holdA, degA);
    gru_compute(c, s, afB, hfB, holdB, degB, bw, bh);
    if (!more) break;
    s = ns;
  }
}

// ---- per-graph counts from SORTED gid: binary search, no atomics
__global__ __launch_bounds__(64) void k_bounds(const int* __restrict__ gid,
                                               int* __restrict__ cnt, int N, int G) {
  int g = threadIdx.x;
  if (g >= G) return;
  int lo = 0, hi = N;
  while (lo < hi) { int mid = (lo + hi) >> 1; if (gid[mid] < g) lo = mid + 1; else hi = mid; }
  int lb0 = lo;
  lo = 0; hi = N;
  int g1 = g + 1;
  while (lo < hi) { int mid = (lo + hi) >> 1; if (gid[mid] < g1) lo = mid + 1; else hi = mid; }
  cnt[g] = lo - lb0;
}

// ---- pooling: graph_ids sorted -> run-length accumulate, few atomics
#define POOL_CHUNK 96
__global__ __launch_bounds__(128) void k_pool(const ushort* __restrict__ hb,
                                              const int* __restrict__ gid,
                                              float* __restrict__ hg, int N) {
  int d = threadIdx.x;
  int start = blockIdx.x * POOL_CHUNK;
  if (start >= N) return;
  int end = min(start + POOL_CHUNK, N);
  float acc = 0.f;
  int g = gid[start];
  for (int n = start; n < end; ++n) {
    int gn = gid[n];
    if (gn != g) { unsafeAtomicAdd(&hg[g * HID + d], acc); acc = 0.f; g = gn; }
    acc += fmaxf(bf2f(hb[(size_t)n * HID + d]), 0.f);   // relu
  }
  unsafeAtomicAdd(&hg[g * HID + d], acc);
}

__global__ __launch_bounds__(640) void k_cls(const float* __restrict__ hg,
                                             const int* __restrict__ cnt,
                                             const float* __restrict__ Wc,
                                             const float* __restrict__ bc,
                                             float* __restrict__ out, int G) {
  int t = threadIdx.x;
  if (t >= G * 10) return;
  int g = t / 10, c = t % 10;
  float inv = 1.f / fmaxf((float)cnt[g], 1.f);
  float acc = 0.f;
  for (int d = 0; d < HID; ++d) acc = fmaf(hg[g * HID + d], Wc[c * HID + d], acc);
  out[t] = acc * inv + bc[c];
}

extern "C" void kernel_launch(void* const* d_in, const int* in_sizes, int n_in,
                              void* d_out, int out_size, void* d_ws, size_t ws_size,
                              hipStream_t stream) {
  const int N = in_sizes[0];
  const int E = in_sizes[9];
  const float* m    = (const float*)d_in[0];
  const float* W_e  = (const float*)d_in[1];
  const float* b_e  = (const float*)d_in[2];
  const float* W_ih = (const float*)d_in[3];
  const float* b_ih = (const float*)d_in[4];
  const float* W_hh = (const float*)d_in[5];
  const float* b_hh = (const float*)d_in[6];
  const float* W_cls = (const float*)d_in[7];
  const float* b_cls = (const float*)d_in[8];
  const int* src = (const int*)d_in[9];
  const int* dst = (const int*)d_in[10];
  const int* gid = (const int*)d_in[11];
  const int G = out_size / 10;
  float* out = (float*)d_out;

  size_t off = 0;
  auto alloc = [&](size_t b) {
    char* p = (char*)d_ws + off;
    off += (b + 255) & ~(size_t)255;
    return (void*)p;
  };
  ushort* hb0    = (ushort*)alloc((size_t)N * HID * 2);
  ushort* hb1    = (ushort*)alloc((size_t)N * HID * 2);
  ushort* hs16   = (ushort*)alloc((size_t)N * HID * 2);
  int*    deg    = (int*)   alloc((size_t)N * 4);
  int*    rowptr = (int*)   alloc((size_t)(N + 1) * 4);
  int*    csrc   = (int*)   alloc((size_t)E * 4);
  uint*   ebuf   = (uint*)  alloc((size_t)E * 4);
  int*    bhist  = (int*)   alloc((size_t)MAXBUK * 4);
  int*    bbase  = (int*)   alloc((size_t)(MAXBUK + 1) * 4);
  int*    gcur   = (int*)   alloc((size_t)MAXBUK * 4);
  ushort* Wcomb  = (ushort*)alloc((size_t)G3 * HID * 2);
  ushort* Whh16  = (ushort*)alloc((size_t)G3 * HID * 2);
  float*  bvec   = (float*) alloc((size_t)G3 * 4);
  float*  hg     = (float*) alloc((size_t)G * HID * 4);
  int*    cnt    = (int*)   alloc((size_t)G * 4);
  if (off > ws_size) return;   // workspace too small -> visible failure

  const int NBUK = (N + BNODES - 1) >> BSHIFT;   // 196 at N=100k (<= MAXBUK)

  k_weights<<<2 * G3, HID, 0, stream>>>(W_e, b_e, W_ih, W_hh, Wcomb, Whh16, bvec);
  hipMemsetAsync(bhist, 0, (size_t)MAXBUK * 4, stream);
  k_bh<<<256, 256, 0, stream>>>(dst, bhist, E);
  k_bsc<<<1, MAXBUK, 0, stream>>>(bhist, bbase, gcur, rowptr, E, N);
  k_part<<<(E + PART_EPB - 1) / PART_EPB, 256, 0, stream>>>(src, dst, gcur, ebuf, E);
  k_fill2<<<NBUK, 256, 0, stream>>>(ebuf, bbase, csrc, rowptr, deg, N);
  k_init<<<(N * HID + 255) / 256, 256, 0, stream>>>(m, hb0, N);

  ushort* hbc = hb0;
  ushort* hbn = hb1;
  for (int s = 0; s < TSTEPS; ++s) {
    k_gather<<<(N + 3) / 4, 256, 0, stream>>>(rowptr, csrc, hbc, hs16, N);
    int nstrip = N >> 4;
    int blocks = nstrip < 1024 ? nstrip : 1024;
    k_gru<<<blocks, 512, 0, stream>>>(hs16, hbc, hbn, Wcomb, Whh16, bvec, b_ih, b_hh, deg, N);
    ushort* t = hbc; hbc = hbn; hbn = t;
  }

  hipMemsetAsync(hg, 0, (size_t)G * HID * 4, stream);
  k_bounds<<<1, 64, 0, stream>>>(gid, cnt, N, G);
  k_pool<<<(N + POOL_CHUNK - 1) / POOL_CHUNK, HID, 0, stream>>>(hbc, gid, hg, N);
  k_cls<<<1, 640, 0, stream>>>(hg, cnt, W_cls, b_cls, out, G);
}